// Round 6
// baseline (999.126 us; speedup 1.0000x reference)
//
#include <hip/hip_runtime.h>
#include <math.h>

// ---------------------------------------------------------------------------
// HyperbolicGraphConvolution (HGCN HypLinear + NodeSelect + HypAct), c=1.
// Round 6: (1) k_gemm pure (reductions/shuffles removed, transposed W stage),
// (2) fused k_chainapply (reduce+scalar chain+apply in one streaming pass),
// (3) fused hist+pick (ticket), parallel scanB, f32 gathers in A, merged
// sum_neigh into gatherC. Score/top-k stays f64 (sel boundary knife-edge).
// ---------------------------------------------------------------------------

#define MAXN_D 0.996      // (1 - 4e-3)/sqrt(c), c=1
#define MAXN_F 0.996f
#define NPB 16            // nodes per block in k_gemm

typedef unsigned long long ull;

__device__ __forceinline__ double wsumd(double v){
#pragma unroll
  for(int o=32;o;o>>=1) v += __shfl_xor(v,o,64);
  return v;
}
// sum within each 16-lane group
__device__ __forceinline__ double qsumd(double v){
#pragma unroll
  for(int o=1;o<16;o<<=1) v += __shfl_xor(v,o,64);
  return v;
}
__device__ __forceinline__ float qsumf(float v){
#pragma unroll
  for(int o=1;o<16;o<<=1) v += __shfl_xor(v,o,64);
  return v;
}
// sum across the 4 groups (same t = lane&15)
__device__ __forceinline__ double gsumd(double v){
  v += __shfl_xor(v,16,64); v += __shfl_xor(v,32,64); return v;
}
__device__ __forceinline__ float gsumf(float v){
  v += __shfl_xor(v,16,64); v += __shfl_xor(v,32,64); return v;
}

// ---- K0: hyp_bias (double) + |hb|^2 + init select state --------------------
__global__ void k_init(const float* __restrict__ bias, double* __restrict__ hb,
                       double* __restrict__ hb2, ull* __restrict__ pref,
                       int* __restrict__ rem, int kth){
  if(threadIdx.x < 64){
    int lane = threadIdx.x;
    double b = (double)bias[lane];
    double n = fmax(sqrt(wsumd(b*b)), 1e-15);
    double e = tanh(n)*b/n;                       // expmap0, sc=1
    double en = fmax(sqrt(wsumd(e*e)), 1e-15);
    if(en > MAXN_D) e *= MAXN_D/en;               // proj
    hb[lane] = e;
    double s2 = wsumd(e*e);
    if(lane==0) *hb2 = s2;
  }
  if(threadIdx.x == 0){ *pref = 0ull; *rem = kth; }
}

// ---- K1: mx = x @ W^T (f64, LDS-tiled, PURE — no reductions) ---------------
__global__ __launch_bounds__(256) void k_gemm(
    const float* __restrict__ x, const float* __restrict__ W,
    double* __restrict__ mx, int N){
  __shared__ double wlds[4096];     // [k][j] flat k*64+j
  __shared__ double xlds[NPB*64];   // [n][k] f64
  int tid = threadIdx.x;
  for(int idx=tid; idx<4096; idx+=256)
    wlds[(idx&63)*64 + (idx>>6)] = (double)W[idx];   // W[j][k] -> wlds[k][j]
  int i0 = blockIdx.x*NPB;
  for(int idx=tid; idx<NPB*64; idx+=256){
    int node = i0 + (idx>>6);
    xlds[idx] = (node<N) ? (double)x[(size_t)node*64 + (idx&63)] : 0.0;
  }
  __syncthreads();
  int lane = tid & 63;
  int nb = (tid>>6)*4;              // this wave's first node-in-block
  double acc0=0.0, acc1=0.0, acc2=0.0, acc3=0.0;
  const double2* x2 = (const double2*)xlds;
#pragma unroll
  for(int k2=0; k2<32; ++k2){
    double wa = wlds[(2*k2)*64 + lane];      // consecutive doubles: 2/bank, free
    double wb = wlds[(2*k2+1)*64 + lane];
    double2 a  = x2[(nb+0)*32 + k2];         // wave-uniform broadcasts
    double2 b  = x2[(nb+1)*32 + k2];
    double2 c  = x2[(nb+2)*32 + k2];
    double2 d  = x2[(nb+3)*32 + k2];
    acc0 = fma(wa, a.x, acc0); acc0 = fma(wb, a.y, acc0);
    acc1 = fma(wa, b.x, acc1); acc1 = fma(wb, b.y, acc1);
    acc2 = fma(wa, c.x, acc2); acc2 = fma(wb, c.y, acc2);
    acc3 = fma(wa, d.x, acc3); acc3 = fma(wb, d.y, acc3);
  }
  {int node=i0+nb+0; if(node<N) mx[(size_t)node*64+lane]=acc0;}
  {int node=i0+nb+1; if(node<N) mx[(size_t)node*64+lane]=acc1;}
  {int node=i0+nb+2; if(node<N) mx[(size_t)node*64+lane]=acc2;}
  {int node=i0+nb+3; if(node<N) mx[(size_t)node*64+lane]=acc3;}
}

// ---- K2: fused reduce + scalar chain + apply (16 lanes per node) -----------
// x_tan = alpha*mx + beta*hb; alpha,beta from r1=|x|^2, r2=|mx|^2, r3=<mx,hb>.
__global__ __launch_bounds__(256) void k_chainapply(
    const float* __restrict__ x, const double* __restrict__ mx,
    const double* __restrict__ hb, const double* __restrict__ hb2p,
    double* __restrict__ xtd, float* __restrict__ xtf, int N){
  int lane = threadIdx.x & 63;
  int wid  = (int)((blockIdx.x*(unsigned)blockDim.x + threadIdx.x)>>6);
  int g = lane>>4, t = lane&15;
  int i = wid*4 + g;
  if(i>=N) return;
  size_t b = (size_t)i*64 + t*4;
  float4  xv = *(const float4*)(x+b);
  double2 m0 = *(const double2*)(mx+b);
  double2 m1 = *(const double2*)(mx+b+2);
  double2 h0 = *(const double2*)(hb+t*4);
  double2 h1 = *(const double2*)(hb+t*4+2);
  double xd0=xv.x, xd1=xv.y, xd2=xv.z, xd3=xv.w;
  double x2s = qsumd(xd0*xd0 + xd1*xd1 + xd2*xd2 + xd3*xd3);
  double m2  = qsumd(m0.x*m0.x + m0.y*m0.y + m1.x*m1.x + m1.y*m1.y);
  double mh  = qsumd(m0.x*h0.x + m0.y*h0.y + m1.x*h1.x + m1.y*h1.y);
  // ---- scalar chain (all 16 lanes of the group compute redundantly) ----
  double y2 = *hb2p;
  double xn  = fmax(sqrt(x2s), 1e-15);
  double mxn = fmax(sqrt(m2), 1e-15);
  double xc  = fmin(fmax(xn, -1.0+1e-7), 1.0-1e-7);
  double at  = 0.5*(log1p(xc)-log1p(-xc));        // artanh(|x|)
  double f1  = tanh(mxn/xn*at)/mxn;               // h = f1*mx, f1 >= 0
  if(m2 == 0.0) f1 = 0.0;                         // zero-mask (all mx==0)
  double h2 = f1*f1*m2;
  double hn = fmax(sqrt(h2), 1e-15);
  if(hn > MAXN_D){ double s = MAXN_D/hn; f1 *= s; h2 = f1*f1*m2; }   // proj(h)
  double xy = f1*mh;                              // <h, hb>
  double den = fmax(1.0 + 2.0*xy + h2*y2, 1e-15);
  double a = (1.0 + 2.0*xy + y2)/den;
  double bb = (1.0 - h2)/den;
  double p2 = a*a*h2 + 2.0*a*bb*xy + bb*bb*y2;    // |p|^2
  double pn = fmax(sqrt(p2), 1e-15);
  if(pn > MAXN_D){ double s = MAXN_D/pn; a*=s; bb*=s; pn = fmax(pn*s, 1e-15); }
  double nc  = fmin(fmax(pn, -1.0+1e-7), 1.0-1e-7);
  double at2 = 0.5*(log1p(nc)-log1p(-nc));        // artanh(|p|)
  double sc  = at2/pn;                            // logmap0 scale
  double al = sc*a*f1, be = sc*bb;
  double2 o0, o1;
  o0.x = al*m0.x + be*h0.x; o0.y = al*m0.y + be*h0.y;
  o1.x = al*m1.x + be*h1.x; o1.y = al*m1.y + be*h1.y;
  *(double2*)(xtd+b)   = o0;
  *(double2*)(xtd+b+2) = o1;
  float4 f; f.x=(float)o0.x; f.y=(float)o0.y; f.z=(float)o1.x; f.w=(float)o1.y;
  *(float4*)(xtf+b) = f;
}

// ---- K3: degrees -----------------------------------------------------------
__global__ void k_count(const int* __restrict__ ei, int* __restrict__ degin,
                        int* __restrict__ degout, int E){
  int e = blockIdx.x*blockDim.x + threadIdx.x;
  if(e < E){
    int s = ei[e], d = ei[(size_t)E+e];
    atomicAdd(&degin[d], 1);
    if(s != d) atomicAdd(&degout[s], 1);
  }
}

// ---- K4: dinv --------------------------------------------------------------
__global__ void k_dinv(const int* __restrict__ degout, double* __restrict__ dinv, int N){
  int i = blockIdx.x*blockDim.x + threadIdx.x;
  if(i<N){ int d = degout[i]; dinv[i] = (d>0) ? 1.0/sqrt((double)d) : 0.0; }
}

// ---- K5a/b/c: exclusive scan of degin -> rowptr (+ cursor copy) ------------
__global__ void k_scanA(const int* __restrict__ degin, int* __restrict__ excl,
                        int* __restrict__ bsum, int N){
  __shared__ int sh[256];
  int i = blockIdx.x*256 + (int)threadIdx.x;
  int v = (i<N) ? degin[i] : 0;
  sh[threadIdx.x] = v;
  __syncthreads();
  for(int off=1; off<256; off<<=1){
    int tv = (threadIdx.x >= (unsigned)off) ? sh[threadIdx.x-off] : 0;
    __syncthreads();
    sh[threadIdx.x] += tv;
    __syncthreads();
  }
  if(i<N) excl[i] = sh[threadIdx.x] - v;
  if(threadIdx.x == 255) bsum[blockIdx.x] = sh[255];
}
// parallel exclusive scan of up to 512 block sums in one block
__global__ void k_scanB(int* __restrict__ bsum, int nb){
  if(nb > 512){                       // safety fallback (not hit at N=100k)
    if(threadIdx.x==0){ int run=0; for(int b=0;b<nb;++b){int t=bsum[b];bsum[b]=run;run+=t;} }
    return;
  }
  __shared__ int sh[512];
  int t = threadIdx.x;
  int v0 = (t<nb)     ? bsum[t]     : 0;
  int v1 = (t+256<nb) ? bsum[t+256] : 0;
  sh[t] = v0; sh[t+256] = v1;
  __syncthreads();
  for(int off=1; off<512; off<<=1){
    int a0 = (t>=off)     ? sh[t-off]     : 0;
    int a1 = (t+256>=off) ? sh[t+256-off] : 0;
    __syncthreads();
    sh[t] += a0; sh[t+256] += a1;
    __syncthreads();
  }
  if(t<nb)     bsum[t]     = sh[t]     - v0;     // exclusive
  if(t+256<nb) bsum[t+256] = sh[t+256] - v1;
}
__global__ void k_scanC(const int* __restrict__ excl, const int* __restrict__ bsum,
                        int* __restrict__ rowptr, int* __restrict__ cursor, int N, int E){
  int i = blockIdx.x*256 + (int)threadIdx.x;
  if(i<N){
    int r = excl[i] + bsum[blockIdx.x];
    rowptr[i] = r; cursor[i] = r;
  }
  if(i==0) rowptr[N] = E;
}

// ---- K6: scatter edges into CSR --------------------------------------------
__global__ void k_scatter(const int* __restrict__ ei, int* __restrict__ cursor,
                          int* __restrict__ csr, int E){
  int e = blockIdx.x*blockDim.x + threadIdx.x;
  if(e < E){
    int s = ei[e], d = ei[(size_t)E+e];
    int pos = atomicAdd(&cursor[d], 1);
    csr[pos] = s;
  }
}

// ---- K7: gather A: info score key (f64 accum over f32 rows) ----------------
__global__ void k_gatherA(const int* __restrict__ csr, const int* __restrict__ rowptr,
                          const float* __restrict__ xtf, const double* __restrict__ xtd,
                          const double* __restrict__ dinv,
                          ull* __restrict__ keys, int N){
  int lane = threadIdx.x & 63;
  int i = (int)((blockIdx.x*(unsigned)blockDim.x + threadIdx.x)>>6);
  if(i>=N) return;
  int beg = rowptr[i], deg = rowptr[i+1]-beg;
  int g = lane>>4, t = lane&15;
  double di = dinv[i];
  double a0=0.0,a1=0.0,a2=0.0,a3=0.0;
  int j = g;
  int s = (j<deg) ? csr[beg+j] : 0;
  while(j < deg){
    int snext = (j+4<deg) ? csr[beg+j+4] : 0;       // prefetch next index
    if(s != i){
      double w = di*dinv[s];
      float4 v = *((const float4*)(xtf + (size_t)s*64 + t*4));
      a0 -= w*(double)v.x; a1 -= w*(double)v.y;
      a2 -= w*(double)v.z; a3 -= w*(double)v.w;
    }
    s = snext; j += 4;
  }
  a0 = gsumd(a0); a1 = gsumd(a1); a2 = gsumd(a2); a3 = gsumd(a3);
  const double2* xr = (const double2*)(xtd + (size_t)i*64 + t*4);
  double2 x0 = xr[0], x1 = xr[1];
  double sc = fabs(x0.x+a0) + fabs(x0.y+a1) + fabs(x1.x+a2) + fabs(x1.y+a3);
  sc = qsumd(sc);
  if(lane==0) keys[i] = (ull)__double_as_longlong(sc);
}

// ---- K8: fused radix level: grid hist + last-block pick (ticket) -----------
__global__ void k_histpick(const ull* __restrict__ keys, int N,
                           ull* __restrict__ pref, int* __restrict__ rem,
                           int lev, int* __restrict__ hist, int* __restrict__ ticket){
  __shared__ int h[256];
  __shared__ int lastflag;
  h[threadIdx.x] = 0;
  __syncthreads();
  int shift = 56 - 8*lev;
  ull p = *pref;                                  // stream-ordered: visible
  for(int i = blockIdx.x*blockDim.x + threadIdx.x; i<N; i += gridDim.x*blockDim.x){
    ull kk = keys[i];
    if(lev==0 || (kk >> (shift+8)) == (p >> (shift+8)))
      atomicAdd(&h[(int)((kk>>shift)&255)], 1);
  }
  __syncthreads();
  if(h[threadIdx.x])
    __hip_atomic_fetch_add(&hist[threadIdx.x], h[threadIdx.x],
                           __ATOMIC_RELAXED, __HIP_MEMORY_SCOPE_AGENT);
  __threadfence();                                // make hist visible
  if(threadIdx.x==0){
    int tk = __hip_atomic_fetch_add(ticket, 1, __ATOMIC_ACQ_REL, __HIP_MEMORY_SCOPE_AGENT);
    lastflag = (tk == (int)gridDim.x - 1);
  }
  __syncthreads();
  if(!lastflag) return;
  // last block: read global hist, pick digit, update pref/rem
  int v = __hip_atomic_load(&hist[threadIdx.x], __ATOMIC_RELAXED, __HIP_MEMORY_SCOPE_AGENT);
  h[threadIdx.x] = v;
  __syncthreads();
  if(threadIdx.x==0){
    int r = *rem, cum = 0, chosen = 0;
    for(int d=255; d>=0; --d){
      cum += h[d];
      if(cum >= r){ chosen = d; r -= (cum - h[d]); break; }
    }
    *rem = r;
    *pref = p | ((ull)chosen << shift);
  }
}

// ---- K9: gather C + gate: sum_neigh AND sum_sel in one sweep ---------------
__global__ void k_gatherC(const int* __restrict__ csr, const int* __restrict__ rowptr,
                          const float* __restrict__ xtf,
                          const ull* __restrict__ keys, const ull* __restrict__ keyT,
                          const float* __restrict__ lww, const float* __restrict__ lwb,
                          float* __restrict__ gate, int N){
  ull T = *keyT;
  int lane = threadIdx.x & 63;
  int i = (int)((blockIdx.x*(unsigned)blockDim.x + threadIdx.x)>>6);
  if(i>=N) return;
  int beg = rowptr[i], deg = rowptr[i+1]-beg;
  int g = lane>>4, t = lane&15;
  float c0=0.f,c1=0.f,c2=0.f,c3=0.f;     // sum_sel
  float n0=0.f,n1=0.f,n2=0.f,n3=0.f;     // sum_neigh
  int j = g;
  int s = (j<deg) ? csr[beg+j] : 0;
  while(j < deg){
    int snext = (j+4<deg) ? csr[beg+j+4] : 0;
    float4 v = *((const float4*)(xtf + (size_t)s*64 + t*4));
    n0 += v.x; n1 += v.y; n2 += v.z; n3 += v.w;
    if(keys[s] > T){ c0 += v.x; c1 += v.y; c2 += v.z; c3 += v.w; }
    s = snext; j += 4;
  }
  c0 = gsumf(c0); c1 = gsumf(c1); c2 = gsumf(c2); c3 = gsumf(c3);
  n0 = gsumf(n0); n1 = gsumf(n1); n2 = gsumf(n2); n3 = gsumf(n3);
  float4 wA = *((const float4*)(lww + t*4));
  float4 wB = *((const float4*)(lww + 64 + t*4));
  float z = c0*wA.x + c1*wA.y + c2*wA.z + c3*wA.w
          + n0*wB.x + n1*wB.y + n2*wB.z + n3*wB.w;
  z = qsumf(z);
  if(lane==0) gate[i] = 1.f/(1.f+expf(-(z+lwb[0])));
}

// ---- K10: gather D + final chain -------------------------------------------
__global__ void k_gatherD(const int* __restrict__ csr, const int* __restrict__ rowptr,
                          const float* __restrict__ xtf,
                          const ull* __restrict__ keys, const ull* __restrict__ keyT,
                          const float* __restrict__ gate,
                          float* __restrict__ out, int N){
  ull T = *keyT;
  int lane = threadIdx.x & 63;
  int i = (int)((blockIdx.x*(unsigned)blockDim.x + threadIdx.x)>>6);
  if(i>=N) return;
  int beg = rowptr[i], deg = rowptr[i+1]-beg;
  int g = lane>>4, t = lane&15;
  float c0=0.f,c1=0.f,c2=0.f,c3=0.f;
  int j = g;
  int s = (j<deg) ? csr[beg+j] : 0;
  while(j < deg){
    int snext = (j+4<deg) ? csr[beg+j+4] : 0;
    if(keys[s] > T){
      float gv = gate[s];
      float4 v = *((const float4*)(xtf + (size_t)s*64 + t*4));
      c0 = fmaf(gv, v.x, c0); c1 = fmaf(gv, v.y, c1);
      c2 = fmaf(gv, v.z, c2); c3 = fmaf(gv, v.w, c3);
    }
    s = snext; j += 4;
  }
  c0 = gsumf(c0); c1 = gsumf(c1); c2 = gsumf(c2); c3 = gsumf(c3);
  float4 xr = *((const float4*)(xtf + (size_t)i*64 + t*4));
  float v0 = xr.x + fmaxf(c0,0.f);
  float v1 = xr.y + fmaxf(c1,0.f);
  float v2 = xr.z + fmaxf(c2,0.f);
  float v3 = xr.w + fmaxf(c3,0.f);
  float n2 = qsumf(v0*v0 + v1*v1 + v2*v2 + v3*v3);
  float n = fmaxf(sqrtf(n2), 1e-15f);
  float f = tanhf(n)/n;                                // expmap0 scale
  float e0=f*v0, e1=f*v1, e2=f*v2, e3=f*v3;
  float en = fmaxf(tanhf(n), 1e-15f);                  // |e| = tanh(n)
  if(en > MAXN_F){ float sf = MAXN_F/en; e0*=sf; e1*=sf; e2*=sf; e3*=sf; }
  e0 = fmaxf(e0,0.f); e1 = fmaxf(e1,0.f); e2 = fmaxf(e2,0.f); e3 = fmaxf(e3,0.f);
  float m2 = qsumf(e0*e0 + e1*e1 + e2*e2 + e3*e3);
  float nb = fmaxf(sqrtf(m2), 1e-15f);
  float f2 = tanhf(nb)/nb;
  float o0=f2*e0, o1=f2*e1, o2=f2*e2, o3=f2*e3;
  float on = fmaxf(tanhf(nb), 1e-15f);
  if(on > MAXN_F){ float sf = MAXN_F/on; o0*=sf; o1*=sf; o2*=sf; o3*=sf; }
  if(g==0){
    float4 ov = make_float4(o0,o1,o2,o3);
    *((float4*)(out + (size_t)i*64 + t*4)) = ov;
  }
}

// ---------------------------------------------------------------------------
extern "C" void kernel_launch(void* const* d_in, const int* in_sizes, int n_in,
                              void* d_out, int out_size, void* d_ws, size_t ws_size,
                              hipStream_t stream){
  const float* x    = (const float*)d_in[0];
  const int*   ei   = (const int*)d_in[1];
  const float* W    = (const float*)d_in[2];
  const float* bias = (const float*)d_in[3];
  const float* lww  = (const float*)d_in[4];
  const float* lwb  = (const float*)d_in[5];
  int N = in_sizes[0]/64;
  int E = in_sizes[1]/2;
  int kth = (int)((double)N*0.75);
  int nb = (N+255)/256;                        // scan blocks

  char* ws = (char*)d_ws;
  size_t cur = 0;
  auto alloc = [&](size_t bytes){ size_t o = cur; cur = (cur + bytes + 255) & ~(size_t)255; return o; };
  size_t o_hb   = alloc(64*sizeof(double));
  size_t o_hb2  = alloc(8);
  size_t o_keyT = alloc(8);
  size_t o_rem  = alloc(4);
  size_t o_zero = cur;                         // ---- zeroed region start ----
  size_t o_hist = alloc(8*256*4);              // per-level hist
  size_t o_tick = alloc(8*4);                  // per-level tickets
  size_t o_din  = alloc((size_t)N*4);
  size_t o_dout = alloc((size_t)N*4);
  size_t zlen   = cur - o_zero;                // ---- zeroed region end ------
  size_t o_excl = alloc((size_t)N*4);
  size_t o_bsum = alloc((size_t)(nb+1)*4);
  size_t o_rowp = alloc((size_t)(N+1)*4);
  size_t o_curs = alloc((size_t)N*4);
  size_t o_csr  = alloc((size_t)E*4);
  size_t o_dinv = alloc((size_t)N*8);
  size_t o_keys = alloc((size_t)N*8);
  size_t o_xtf  = alloc((size_t)N*64*4);
  size_t o_xtd  = alloc((size_t)N*64*8);
  size_t o_mx   = alloc((size_t)N*64*8);
  size_t o_gate = alloc((size_t)N*4);
  if(ws_size < cur) return;                    // loud, clean failure if ws too small

  double* hb     = (double*)(ws+o_hb);
  double* hb2    = (double*)(ws+o_hb2);
  ull*    keyT   = (ull*)(ws+o_keyT);
  int*    rem    = (int*)(ws+o_rem);
  int*    hist   = (int*)(ws+o_hist);
  int*    tick   = (int*)(ws+o_tick);
  int*    degin  = (int*)(ws+o_din);
  int*    degout = (int*)(ws+o_dout);
  int*    excl   = (int*)(ws+o_excl);
  int*    bsum   = (int*)(ws+o_bsum);
  int*    rowptr = (int*)(ws+o_rowp);
  int*    cursor = (int*)(ws+o_curs);
  int*    csr    = (int*)(ws+o_csr);
  double* dinv   = (double*)(ws+o_dinv);
  ull*    keys   = (ull*)(ws+o_keys);
  float*  xtf    = (float*)(ws+o_xtf);
  double* xtd    = (double*)(ws+o_xtd);
  double* mx     = (double*)(ws+o_mx);
  float*  gate   = (float*)(ws+o_gate);

  hipMemsetAsync(ws+o_zero, 0, zlen, stream);

  int nodeBlocks = (N+3)/4;                    // 1 wave per node, 4 waves/block
  int caBlocks   = (N+15)/16;                  // 4 nodes per wave
  k_init      <<<1, 64, 0, stream>>>(bias, hb, hb2, keyT, rem, kth);
  k_gemm      <<<(N+NPB-1)/NPB, 256, 0, stream>>>(x, W, mx, N);
  k_chainapply<<<caBlocks, 256, 0, stream>>>(x, mx, hb, hb2, xtd, xtf, N);
  k_count     <<<(E+255)/256, 256, 0, stream>>>(ei, degin, degout, E);
  k_dinv      <<<(N+255)/256, 256, 0, stream>>>(degout, dinv, N);
  k_scanA     <<<nb, 256, 0, stream>>>(degin, excl, bsum, N);
  k_scanB     <<<1, 256, 0, stream>>>(bsum, nb);
  k_scanC     <<<nb, 256, 0, stream>>>(excl, bsum, rowptr, cursor, N, E);
  k_scatter   <<<(E+255)/256, 256, 0, stream>>>(ei, cursor, csr, E);
  k_gatherA   <<<nodeBlocks, 256, 0, stream>>>(csr, rowptr, xtf, xtd, dinv, keys, N);
  for(int lev=0; lev<8; ++lev)
    k_histpick<<<256, 256, 0, stream>>>(keys, N, keyT, rem, lev, hist+lev*256, tick+lev);
  k_gatherC   <<<nodeBlocks, 256, 0, stream>>>(csr, rowptr, xtf, keys, keyT, lww, lwb, gate, N);
  k_gatherD   <<<nodeBlocks, 256, 0, stream>>>(csr, rowptr, xtf, keys, keyT, gate, (float*)d_out, N);
}

// Round 7
// 700.529 us; speedup vs baseline: 1.4262x; 1.4262x over previous
//
#include <hip/hip_runtime.h>
#include <math.h>

// ---------------------------------------------------------------------------
// HyperbolicGraphConvolution (HGCN HypLinear + NodeSelect + HypAct), c=1.
// Round 7: revert round-6 gemm regression (full-unroll -> VGPR 256 -> scratch
// spill 775MB). k_gemm = round-5 inner loop (unroll 4, double2) but pure.
// Chain path: k_reduce (16-lane groups) + k_chain (1 thr/node, 64 nodes/wave)
// + k_apply streaming. Keep round-6 wins: fused histpick, par scanB, f32
// gatherA, merged sum_neigh in gatherC. Score/top-k stays f64.
// ---------------------------------------------------------------------------

#define MAXN_D 0.996      // (1 - 4e-3)/sqrt(c), c=1
#define MAXN_F 0.996f
#define NPB 16            // nodes per block in k_gemm

typedef unsigned long long ull;

__device__ __forceinline__ double wsumd(double v){
#pragma unroll
  for(int o=32;o;o>>=1) v += __shfl_xor(v,o,64);
  return v;
}
// sum within each 16-lane group
__device__ __forceinline__ double qsumd(double v){
#pragma unroll
  for(int o=1;o<16;o<<=1) v += __shfl_xor(v,o,64);
  return v;
}
__device__ __forceinline__ float qsumf(float v){
#pragma unroll
  for(int o=1;o<16;o<<=1) v += __shfl_xor(v,o,64);
  return v;
}
// sum across the 4 groups (same t = lane&15)
__device__ __forceinline__ double gsumd(double v){
  v += __shfl_xor(v,16,64); v += __shfl_xor(v,32,64); return v;
}
__device__ __forceinline__ float gsumf(float v){
  v += __shfl_xor(v,16,64); v += __shfl_xor(v,32,64); return v;
}

// ---- K0: hyp_bias (double) + |hb|^2 + init select state --------------------
__global__ void k_init(const float* __restrict__ bias, double* __restrict__ hb,
                       double* __restrict__ hb2, ull* __restrict__ pref,
                       int* __restrict__ rem, int kth){
  if(threadIdx.x < 64){
    int lane = threadIdx.x;
    double b = (double)bias[lane];
    double n = fmax(sqrt(wsumd(b*b)), 1e-15);
    double e = tanh(n)*b/n;                       // expmap0, sc=1
    double en = fmax(sqrt(wsumd(e*e)), 1e-15);
    if(en > MAXN_D) e *= MAXN_D/en;               // proj
    hb[lane] = e;
    double s2 = wsumd(e*e);
    if(lane==0) *hb2 = s2;
  }
  if(threadIdx.x == 0){ *pref = 0ull; *rem = kth; }
}

// ---- K1: mx = x @ W^T (f64, LDS-tiled, round-5 structure, pure) ------------
__global__ __launch_bounds__(256) void k_gemm(
    const float* __restrict__ x, const float* __restrict__ W,
    double* __restrict__ mx, int N){
  __shared__ double wlds[4096];     // double2 [k2][j]: flat (k>>1)*128 + j*2 + (k&1)
  __shared__ double xlds[NPB*64];   // [n][k] f64
  int tid = threadIdx.x;
  for(int idx=tid; idx<4096; idx+=256){
    int j = idx>>6, k = idx&63;
    wlds[(k>>1)*128 + j*2 + (k&1)] = (double)W[idx];
  }
  int i0 = blockIdx.x*NPB;
  for(int idx=tid; idx<NPB*64; idx+=256){
    int node = i0 + (idx>>6);
    xlds[idx] = (node<N) ? (double)x[(size_t)node*64 + (idx&63)] : 0.0;
  }
  __syncthreads();
  int lane = tid & 63;
  int nb = (tid>>6)*4;              // this wave's first node-in-block
  double acc0=0.0, acc1=0.0, acc2=0.0, acc3=0.0;
  const double2* w2 = (const double2*)wlds;
  const double2* x2 = (const double2*)xlds;
#pragma unroll 4
  for(int k2=0; k2<32; ++k2){
    double2 wt = w2[k2*64 + lane];          // contiguous b128 across lanes
    double2 a  = x2[(nb+0)*32 + k2];        // wave-uniform broadcasts
    double2 b  = x2[(nb+1)*32 + k2];
    double2 c  = x2[(nb+2)*32 + k2];
    double2 d  = x2[(nb+3)*32 + k2];
    acc0 = fma(wt.x, a.x, acc0); acc0 = fma(wt.y, a.y, acc0);
    acc1 = fma(wt.x, b.x, acc1); acc1 = fma(wt.y, b.y, acc1);
    acc2 = fma(wt.x, c.x, acc2); acc2 = fma(wt.y, c.y, acc2);
    acc3 = fma(wt.x, d.x, acc3); acc3 = fma(wt.y, d.y, acc3);
  }
  {int node=i0+nb+0; if(node<N) mx[(size_t)node*64+lane]=acc0;}
  {int node=i0+nb+1; if(node<N) mx[(size_t)node*64+lane]=acc1;}
  {int node=i0+nb+2; if(node<N) mx[(size_t)node*64+lane]=acc2;}
  {int node=i0+nb+3; if(node<N) mx[(size_t)node*64+lane]=acc3;}
}

// ---- K2: r1=|x|^2, r2=|mx|^2, r3=<mx,hb> (16 lanes/node, streaming) --------
__global__ __launch_bounds__(256) void k_reduce(
    const float* __restrict__ x, const double* __restrict__ mx,
    const double* __restrict__ hb,
    double* __restrict__ r1, double* __restrict__ r2, double* __restrict__ r3,
    int N){
  int lane = threadIdx.x & 63;
  int wid  = (int)((blockIdx.x*(unsigned)blockDim.x + threadIdx.x)>>6);
  int g = lane>>4, t = lane&15;
  int i = wid*4 + g;
  if(i>=N) return;
  size_t b = (size_t)i*64 + t*4;
  float4  xv = *(const float4*)(x+b);
  double2 m0 = *(const double2*)(mx+b);
  double2 m1 = *(const double2*)(mx+b+2);
  double2 h0 = *(const double2*)(hb+t*4);
  double2 h1 = *(const double2*)(hb+t*4+2);
  double s1 = qsumd((double)xv.x*xv.x + (double)xv.y*xv.y
                  + (double)xv.z*xv.z + (double)xv.w*xv.w);
  double s2 = qsumd(m0.x*m0.x + m0.y*m0.y + m1.x*m1.x + m1.y*m1.y);
  double s3 = qsumd(m0.x*h0.x + m0.y*h0.y + m1.x*h1.x + m1.y*h1.y);
  if(t==0){ r1[i]=s1; r2[i]=s2; r3[i]=s3; }
}

// ---- K3: per-node scalar chain (one THREAD per node) -> alpha, beta --------
__global__ void k_chain(const double* __restrict__ r1, const double* __restrict__ r2,
                        const double* __restrict__ r3, const double* __restrict__ hb2p,
                        double* __restrict__ alpha, double* __restrict__ beta, int N){
  int i = blockIdx.x*blockDim.x + threadIdx.x;
  if(i>=N) return;
  double x2s = r1[i], m2 = r2[i], mh = r3[i];
  double y2 = *hb2p;
  double xn  = fmax(sqrt(x2s), 1e-15);
  double mxn = fmax(sqrt(m2), 1e-15);
  double xc  = fmin(fmax(xn, -1.0+1e-7), 1.0-1e-7);
  double at  = 0.5*(log1p(xc)-log1p(-xc));        // artanh(|x|)
  double f1  = tanh(mxn/xn*at)/mxn;               // h = f1*mx, f1 >= 0
  if(m2 == 0.0) f1 = 0.0;                         // zero-mask (all mx==0)
  double h2 = f1*f1*m2;
  double hn = fmax(sqrt(h2), 1e-15);
  if(hn > MAXN_D){ double s = MAXN_D/hn; f1 *= s; h2 = f1*f1*m2; }   // proj(h)
  double xy = f1*mh;                              // <h, hb>
  double den = fmax(1.0 + 2.0*xy + h2*y2, 1e-15);
  double a = (1.0 + 2.0*xy + y2)/den;
  double b = (1.0 - h2)/den;
  double p2 = a*a*h2 + 2.0*a*b*xy + b*b*y2;       // |p|^2
  double pn = fmax(sqrt(p2), 1e-15);
  if(pn > MAXN_D){ double s = MAXN_D/pn; a*=s; b*=s; pn = fmax(pn*s, 1e-15); }
  double nc  = fmin(fmax(pn, -1.0+1e-7), 1.0-1e-7);
  double at2 = 0.5*(log1p(nc)-log1p(-nc));        // artanh(|p|)
  double sc  = at2/pn;                            // logmap0 scale
  alpha[i] = sc*a*f1;
  beta[i]  = sc*b;
}

// ---- K4: x_tan = alpha*mx + beta*hb (double2 streaming) --------------------
__global__ void k_apply(const double* __restrict__ mx, const double* __restrict__ alpha,
                        const double* __restrict__ beta, const double* __restrict__ hb,
                        double* __restrict__ xtd, float* __restrict__ xtf, int N){
  size_t idx = ((size_t)blockIdx.x*blockDim.x + threadIdx.x)*2;
  if(idx >= (size_t)N*64) return;
  int i = (int)(idx>>6);
  double al = alpha[i], be = beta[i];
  double2 m  = *(const double2*)(mx+idx);
  double2 hv = *(const double2*)(hb+(idx&63));
  double2 v; v.x = al*m.x + be*hv.x; v.y = al*m.y + be*hv.y;
  *(double2*)(xtd+idx) = v;
  float2 f; f.x = (float)v.x; f.y = (float)v.y;
  *(float2*)(xtf+idx) = f;
}

// ---- K5: degrees -----------------------------------------------------------
__global__ void k_count(const int* __restrict__ ei, int* __restrict__ degin,
                        int* __restrict__ degout, int E){
  int e = blockIdx.x*blockDim.x + threadIdx.x;
  if(e < E){
    int s = ei[e], d = ei[(size_t)E+e];
    atomicAdd(&degin[d], 1);
    if(s != d) atomicAdd(&degout[s], 1);
  }
}

// ---- K6: dinv --------------------------------------------------------------
__global__ void k_dinv(const int* __restrict__ degout, double* __restrict__ dinv, int N){
  int i = blockIdx.x*blockDim.x + threadIdx.x;
  if(i<N){ int d = degout[i]; dinv[i] = (d>0) ? 1.0/sqrt((double)d) : 0.0; }
}

// ---- K7a/b/c: exclusive scan of degin -> rowptr (+ cursor copy) ------------
__global__ void k_scanA(const int* __restrict__ degin, int* __restrict__ excl,
                        int* __restrict__ bsum, int N){
  __shared__ int sh[256];
  int i = blockIdx.x*256 + (int)threadIdx.x;
  int v = (i<N) ? degin[i] : 0;
  sh[threadIdx.x] = v;
  __syncthreads();
  for(int off=1; off<256; off<<=1){
    int tv = (threadIdx.x >= (unsigned)off) ? sh[threadIdx.x-off] : 0;
    __syncthreads();
    sh[threadIdx.x] += tv;
    __syncthreads();
  }
  if(i<N) excl[i] = sh[threadIdx.x] - v;
  if(threadIdx.x == 255) bsum[blockIdx.x] = sh[255];
}
__global__ void k_scanB(int* __restrict__ bsum, int nb){
  if(nb > 512){
    if(threadIdx.x==0){ int run=0; for(int b=0;b<nb;++b){int t=bsum[b];bsum[b]=run;run+=t;} }
    return;
  }
  __shared__ int sh[512];
  int t = threadIdx.x;
  int v0 = (t<nb)     ? bsum[t]     : 0;
  int v1 = (t+256<nb) ? bsum[t+256] : 0;
  sh[t] = v0; sh[t+256] = v1;
  __syncthreads();
  for(int off=1; off<512; off<<=1){
    int a0 = (t>=off)     ? sh[t-off]     : 0;
    int a1 = (t+256>=off) ? sh[t+256-off] : 0;
    __syncthreads();
    sh[t] += a0; sh[t+256] += a1;
    __syncthreads();
  }
  if(t<nb)     bsum[t]     = sh[t]     - v0;     // exclusive
  if(t+256<nb) bsum[t+256] = sh[t+256] - v1;
}
__global__ void k_scanC(const int* __restrict__ excl, const int* __restrict__ bsum,
                        int* __restrict__ rowptr, int* __restrict__ cursor, int N, int E){
  int i = blockIdx.x*256 + (int)threadIdx.x;
  if(i<N){
    int r = excl[i] + bsum[blockIdx.x];
    rowptr[i] = r; cursor[i] = r;
  }
  if(i==0) rowptr[N] = E;
}

// ---- K8: scatter edges into CSR --------------------------------------------
__global__ void k_scatter(const int* __restrict__ ei, int* __restrict__ cursor,
                          int* __restrict__ csr, int E){
  int e = blockIdx.x*blockDim.x + threadIdx.x;
  if(e < E){
    int s = ei[e], d = ei[(size_t)E+e];
    int pos = atomicAdd(&cursor[d], 1);
    csr[pos] = s;
  }
}

// ---- K9: gather A: info score key (f64 accum over f32 rows) ----------------
__global__ void k_gatherA(const int* __restrict__ csr, const int* __restrict__ rowptr,
                          const float* __restrict__ xtf, const double* __restrict__ xtd,
                          const double* __restrict__ dinv,
                          ull* __restrict__ keys, int N){
  int lane = threadIdx.x & 63;
  int i = (int)((blockIdx.x*(unsigned)blockDim.x + threadIdx.x)>>6);
  if(i>=N) return;
  int beg = rowptr[i], deg = rowptr[i+1]-beg;
  int g = lane>>4, t = lane&15;
  double di = dinv[i];
  double a0=0.0,a1=0.0,a2=0.0,a3=0.0;
  int j = g;
  int s = (j<deg) ? csr[beg+j] : 0;
  while(j < deg){
    int snext = (j+4<deg) ? csr[beg+j+4] : 0;       // prefetch next index
    if(s != i){
      double w = di*dinv[s];
      float4 v = *((const float4*)(xtf + (size_t)s*64 + t*4));
      a0 -= w*(double)v.x; a1 -= w*(double)v.y;
      a2 -= w*(double)v.z; a3 -= w*(double)v.w;
    }
    s = snext; j += 4;
  }
  a0 = gsumd(a0); a1 = gsumd(a1); a2 = gsumd(a2); a3 = gsumd(a3);
  const double2* xr = (const double2*)(xtd + (size_t)i*64 + t*4);
  double2 x0 = xr[0], x1 = xr[1];
  double sc = fabs(x0.x+a0) + fabs(x0.y+a1) + fabs(x1.x+a2) + fabs(x1.y+a3);
  sc = qsumd(sc);
  if(lane==0) keys[i] = (ull)__double_as_longlong(sc);
}

// ---- K10: fused radix level: grid hist + last-block pick (ticket) ----------
__global__ void k_histpick(const ull* __restrict__ keys, int N,
                           ull* __restrict__ pref, int* __restrict__ rem,
                           int lev, int* __restrict__ hist, int* __restrict__ ticket){
  __shared__ int h[256];
  __shared__ int lastflag;
  h[threadIdx.x] = 0;
  __syncthreads();
  int shift = 56 - 8*lev;
  ull p = *pref;                                  // stream-ordered: visible
  for(int i = blockIdx.x*blockDim.x + threadIdx.x; i<N; i += gridDim.x*blockDim.x){
    ull kk = keys[i];
    if(lev==0 || (kk >> (shift+8)) == (p >> (shift+8)))
      atomicAdd(&h[(int)((kk>>shift)&255)], 1);
  }
  __syncthreads();
  if(h[threadIdx.x])
    __hip_atomic_fetch_add(&hist[threadIdx.x], h[threadIdx.x],
                           __ATOMIC_RELAXED, __HIP_MEMORY_SCOPE_AGENT);
  __threadfence();                                // make hist visible
  if(threadIdx.x==0){
    int tk = __hip_atomic_fetch_add(ticket, 1, __ATOMIC_ACQ_REL, __HIP_MEMORY_SCOPE_AGENT);
    lastflag = (tk == (int)gridDim.x - 1);
  }
  __syncthreads();
  if(!lastflag) return;
  int v = __hip_atomic_load(&hist[threadIdx.x], __ATOMIC_RELAXED, __HIP_MEMORY_SCOPE_AGENT);
  h[threadIdx.x] = v;
  __syncthreads();
  if(threadIdx.x==0){
    int r = *rem, cum = 0, chosen = 0;
    for(int d=255; d>=0; --d){
      cum += h[d];
      if(cum >= r){ chosen = d; r -= (cum - h[d]); break; }
    }
    *rem = r;
    *pref = p | ((ull)chosen << shift);
  }
}

// ---- K11: gather C + gate: sum_neigh AND sum_sel in one sweep --------------
__global__ void k_gatherC(const int* __restrict__ csr, const int* __restrict__ rowptr,
                          const float* __restrict__ xtf,
                          const ull* __restrict__ keys, const ull* __restrict__ keyT,
                          const float* __restrict__ lww, const float* __restrict__ lwb,
                          float* __restrict__ gate, int N){
  ull T = *keyT;
  int lane = threadIdx.x & 63;
  int i = (int)((blockIdx.x*(unsigned)blockDim.x + threadIdx.x)>>6);
  if(i>=N) return;
  int beg = rowptr[i], deg = rowptr[i+1]-beg;
  int g = lane>>4, t = lane&15;
  float c0=0.f,c1=0.f,c2=0.f,c3=0.f;     // sum_sel
  float n0=0.f,n1=0.f,n2=0.f,n3=0.f;     // sum_neigh
  int j = g;
  int s = (j<deg) ? csr[beg+j] : 0;
  while(j < deg){
    int snext = (j+4<deg) ? csr[beg+j+4] : 0;
    float4 v = *((const float4*)(xtf + (size_t)s*64 + t*4));
    n0 += v.x; n1 += v.y; n2 += v.z; n3 += v.w;
    if(keys[s] > T){ c0 += v.x; c1 += v.y; c2 += v.z; c3 += v.w; }
    s = snext; j += 4;
  }
  c0 = gsumf(c0); c1 = gsumf(c1); c2 = gsumf(c2); c3 = gsumf(c3);
  n0 = gsumf(n0); n1 = gsumf(n1); n2 = gsumf(n2); n3 = gsumf(n3);
  float4 wA = *((const float4*)(lww + t*4));
  float4 wB = *((const float4*)(lww + 64 + t*4));
  float z = c0*wA.x + c1*wA.y + c2*wA.z + c3*wA.w
          + n0*wB.x + n1*wB.y + n2*wB.z + n3*wB.w;
  z = qsumf(z);
  if(lane==0) gate[i] = 1.f/(1.f+expf(-(z+lwb[0])));
}

// ---- K12: gather D + final chain -------------------------------------------
__global__ void k_gatherD(const int* __restrict__ csr, const int* __restrict__ rowptr,
                          const float* __restrict__ xtf,
                          const ull* __restrict__ keys, const ull* __restrict__ keyT,
                          const float* __restrict__ gate,
                          float* __restrict__ out, int N){
  ull T = *keyT;
  int lane = threadIdx.x & 63;
  int i = (int)((blockIdx.x*(unsigned)blockDim.x + threadIdx.x)>>6);
  if(i>=N) return;
  int beg = rowptr[i], deg = rowptr[i+1]-beg;
  int g = lane>>4, t = lane&15;
  float c0=0.f,c1=0.f,c2=0.f,c3=0.f;
  int j = g;
  int s = (j<deg) ? csr[beg+j] : 0;
  while(j < deg){
    int snext = (j+4<deg) ? csr[beg+j+4] : 0;
    if(keys[s] > T){
      float gv = gate[s];
      float4 v = *((const float4*)(xtf + (size_t)s*64 + t*4));
      c0 = fmaf(gv, v.x, c0); c1 = fmaf(gv, v.y, c1);
      c2 = fmaf(gv, v.z, c2); c3 = fmaf(gv, v.w, c3);
    }
    s = snext; j += 4;
  }
  c0 = gsumf(c0); c1 = gsumf(c1); c2 = gsumf(c2); c3 = gsumf(c3);
  float4 xr = *((const float4*)(xtf + (size_t)i*64 + t*4));
  float v0 = xr.x + fmaxf(c0,0.f);
  float v1 = xr.y + fmaxf(c1,0.f);
  float v2 = xr.z + fmaxf(c2,0.f);
  float v3 = xr.w + fmaxf(c3,0.f);
  float n2 = qsumf(v0*v0 + v1*v1 + v2*v2 + v3*v3);
  float n = fmaxf(sqrtf(n2), 1e-15f);
  float f = tanhf(n)/n;                                // expmap0 scale
  float e0=f*v0, e1=f*v1, e2=f*v2, e3=f*v3;
  float en = fmaxf(tanhf(n), 1e-15f);                  // |e| = tanh(n)
  if(en > MAXN_F){ float sf = MAXN_F/en; e0*=sf; e1*=sf; e2*=sf; e3*=sf; }
  e0 = fmaxf(e0,0.f); e1 = fmaxf(e1,0.f); e2 = fmaxf(e2,0.f); e3 = fmaxf(e3,0.f);
  float m2 = qsumf(e0*e0 + e1*e1 + e2*e2 + e3*e3);
  float nb = fmaxf(sqrtf(m2), 1e-15f);
  float f2 = tanhf(nb)/nb;
  float o0=f2*e0, o1=f2*e1, o2=f2*e2, o3=f2*e3;
  float on = fmaxf(tanhf(nb), 1e-15f);
  if(on > MAXN_F){ float sf = MAXN_F/on; o0*=sf; o1*=sf; o2*=sf; o3*=sf; }
  if(g==0){
    float4 ov = make_float4(o0,o1,o2,o3);
    *((float4*)(out + (size_t)i*64 + t*4)) = ov;
  }
}

// ---------------------------------------------------------------------------
extern "C" void kernel_launch(void* const* d_in, const int* in_sizes, int n_in,
                              void* d_out, int out_size, void* d_ws, size_t ws_size,
                              hipStream_t stream){
  const float* x    = (const float*)d_in[0];
  const int*   ei   = (const int*)d_in[1];
  const float* W    = (const float*)d_in[2];
  const float* bias = (const float*)d_in[3];
  const float* lww  = (const float*)d_in[4];
  const float* lwb  = (const float*)d_in[5];
  int N = in_sizes[0]/64;
  int E = in_sizes[1]/2;
  int kth = (int)((double)N*0.75);
  int nb = (N+255)/256;                        // scan blocks

  char* ws = (char*)d_ws;
  size_t cur = 0;
  auto alloc = [&](size_t bytes){ size_t o = cur; cur = (cur + bytes + 255) & ~(size_t)255; return o; };
  size_t o_hb   = alloc(64*sizeof(double));
  size_t o_hb2  = alloc(8);
  size_t o_keyT = alloc(8);
  size_t o_rem  = alloc(4);
  size_t o_zero = cur;                         // ---- zeroed region start ----
  size_t o_hist = alloc(8*256*4);              // per-level hist
  size_t o_tick = alloc(8*4);                  // per-level tickets
  size_t o_din  = alloc((size_t)N*4);
  size_t o_dout = alloc((size_t)N*4);
  size_t zlen   = cur - o_zero;                // ---- zeroed region end ------
  size_t o_excl = alloc((size_t)N*4);
  size_t o_bsum = alloc((size_t)(nb+1)*4);
  size_t o_rowp = alloc((size_t)(N+1)*4);
  size_t o_curs = alloc((size_t)N*4);
  size_t o_csr  = alloc((size_t)E*4);
  size_t o_dinv = alloc((size_t)N*8);
  size_t o_keys = alloc((size_t)N*8);
  size_t o_xtf  = alloc((size_t)N*64*4);
  size_t o_xtd  = alloc((size_t)N*64*8);
  size_t o_mx   = alloc((size_t)N*64*8);
  size_t o_r1   = alloc((size_t)N*8);
  size_t o_r2   = alloc((size_t)N*8);
  size_t o_r3   = alloc((size_t)N*8);
  size_t o_al   = alloc((size_t)N*8);
  size_t o_be   = alloc((size_t)N*8);
  size_t o_gate = alloc((size_t)N*4);
  if(ws_size < cur) return;                    // loud, clean failure if ws too small

  double* hb     = (double*)(ws+o_hb);
  double* hb2    = (double*)(ws+o_hb2);
  ull*    keyT   = (ull*)(ws+o_keyT);
  int*    rem    = (int*)(ws+o_rem);
  int*    hist   = (int*)(ws+o_hist);
  int*    tick   = (int*)(ws+o_tick);
  int*    degin  = (int*)(ws+o_din);
  int*    degout = (int*)(ws+o_dout);
  int*    excl   = (int*)(ws+o_excl);
  int*    bsum   = (int*)(ws+o_bsum);
  int*    rowptr = (int*)(ws+o_rowp);
  int*    cursor = (int*)(ws+o_curs);
  int*    csr    = (int*)(ws+o_csr);
  double* dinv   = (double*)(ws+o_dinv);
  ull*    keys   = (ull*)(ws+o_keys);
  float*  xtf    = (float*)(ws+o_xtf);
  double* xtd    = (double*)(ws+o_xtd);
  double* mx     = (double*)(ws+o_mx);
  double* r1     = (double*)(ws+o_r1);
  double* r2     = (double*)(ws+o_r2);
  double* r3     = (double*)(ws+o_r3);
  double* alpha  = (double*)(ws+o_al);
  double* beta   = (double*)(ws+o_be);
  float*  gate   = (float*)(ws+o_gate);

  hipMemsetAsync(ws+o_zero, 0, zlen, stream);

  int nodeBlocks = (N+3)/4;                    // 1 wave per node, 4 waves/block
  int rBlocks    = (N+15)/16;                  // 4 nodes per wave (k_reduce)
  k_init    <<<1, 64, 0, stream>>>(bias, hb, hb2, keyT, rem, kth);
  k_gemm    <<<(N+NPB-1)/NPB, 256, 0, stream>>>(x, W, mx, N);
  k_reduce  <<<rBlocks, 256, 0, stream>>>(x, mx, hb, r1, r2, r3, N);
  k_chain   <<<(N+255)/256, 256, 0, stream>>>(r1, r2, r3, hb2, alpha, beta, N);
  k_apply   <<<(N*32+255)/256, 256, 0, stream>>>(mx, alpha, beta, hb, xtd, xtf, N);
  k_count   <<<(E+255)/256, 256, 0, stream>>>(ei, degin, degout, E);
  k_dinv    <<<(N+255)/256, 256, 0, stream>>>(degout, dinv, N);
  k_scanA   <<<nb, 256, 0, stream>>>(degin, excl, bsum, N);
  k_scanB   <<<1, 256, 0, stream>>>(bsum, nb);
  k_scanC   <<<nb, 256, 0, stream>>>(excl, bsum, rowptr, cursor, N, E);
  k_scatter <<<(E+255)/256, 256, 0, stream>>>(ei, cursor, csr, E);
  k_gatherA <<<nodeBlocks, 256, 0, stream>>>(csr, rowptr, xtf, xtd, dinv, keys, N);
  for(int lev=0; lev<8; ++lev)
    k_histpick<<<256, 256, 0, stream>>>(keys, N, keyT, rem, lev, hist+lev*256, tick+lev);
  k_gatherC <<<nodeBlocks, 256, 0, stream>>>(csr, rowptr, xtf, keys, keyT, lww, lwb, gate, N);
  k_gatherD <<<nodeBlocks, 256, 0, stream>>>(csr, rowptr, xtf, keys, keyT, gate, (float*)d_out, N);
}

// Round 8
// 569.606 us; speedup vs baseline: 1.7541x; 1.2298x over previous
//
#include <hip/hip_runtime.h>
#include <math.h>

// ---------------------------------------------------------------------------
// HyperbolicGraphConvolution (HGCN HypLinear + NodeSelect + HypAct), c=1.
// Round 8: counting-sort CSR build. Round-7 profile: k_count+k_scatter=188us,
// WRITE_SIZE 75-83MB = 64B-line write-allocate per random 4B atomic. Replace
// with 256-node buckets: LDS histograms + line-dense binned writes + per-
// bucket LDS count/scan/scatter (csr region L2-compact). degout/dinv from
// src-binning. Rest identical to round 7. Score/top-k stays f64.
// ---------------------------------------------------------------------------

#define MAXN_D 0.996      // (1 - 4e-3)/sqrt(c), c=1
#define MAXN_F 0.996f
#define NPB 16            // nodes per block in k_gemm
#define NBMAX 512         // max buckets (N <= 131072)
#define BINBLK 256        // blocks in bin kernels

typedef unsigned long long ull;

__device__ __forceinline__ double wsumd(double v){
#pragma unroll
  for(int o=32;o;o>>=1) v += __shfl_xor(v,o,64);
  return v;
}
__device__ __forceinline__ double qsumd(double v){
#pragma unroll
  for(int o=1;o<16;o<<=1) v += __shfl_xor(v,o,64);
  return v;
}
__device__ __forceinline__ float qsumf(float v){
#pragma unroll
  for(int o=1;o<16;o<<=1) v += __shfl_xor(v,o,64);
  return v;
}
__device__ __forceinline__ double gsumd(double v){
  v += __shfl_xor(v,16,64); v += __shfl_xor(v,32,64); return v;
}
__device__ __forceinline__ float gsumf(float v){
  v += __shfl_xor(v,16,64); v += __shfl_xor(v,32,64); return v;
}

// ---- K0: hyp_bias (double) + |hb|^2 + init select state --------------------
__global__ void k_init(const float* __restrict__ bias, double* __restrict__ hb,
                       double* __restrict__ hb2, ull* __restrict__ pref,
                       int* __restrict__ rem, int kth){
  if(threadIdx.x < 64){
    int lane = threadIdx.x;
    double b = (double)bias[lane];
    double n = fmax(sqrt(wsumd(b*b)), 1e-15);
    double e = tanh(n)*b/n;                       // expmap0, sc=1
    double en = fmax(sqrt(wsumd(e*e)), 1e-15);
    if(en > MAXN_D) e *= MAXN_D/en;               // proj
    hb[lane] = e;
    double s2 = wsumd(e*e);
    if(lane==0) *hb2 = s2;
  }
  if(threadIdx.x == 0){ *pref = 0ull; *rem = kth; }
}

// ---- K1: mx = x @ W^T (f64, LDS-tiled, pure) -------------------------------
__global__ __launch_bounds__(256) void k_gemm(
    const float* __restrict__ x, const float* __restrict__ W,
    double* __restrict__ mx, int N){
  __shared__ double wlds[4096];     // double2 [k2][j]: flat (k>>1)*128 + j*2 + (k&1)
  __shared__ double xlds[NPB*64];   // [n][k] f64
  int tid = threadIdx.x;
  for(int idx=tid; idx<4096; idx+=256){
    int j = idx>>6, k = idx&63;
    wlds[(k>>1)*128 + j*2 + (k&1)] = (double)W[idx];
  }
  int i0 = blockIdx.x*NPB;
  for(int idx=tid; idx<NPB*64; idx+=256){
    int node = i0 + (idx>>6);
    xlds[idx] = (node<N) ? (double)x[(size_t)node*64 + (idx&63)] : 0.0;
  }
  __syncthreads();
  int lane = tid & 63;
  int nb = (tid>>6)*4;
  double acc0=0.0, acc1=0.0, acc2=0.0, acc3=0.0;
  const double2* w2 = (const double2*)wlds;
  const double2* x2 = (const double2*)xlds;
#pragma unroll 4
  for(int k2=0; k2<32; ++k2){
    double2 wt = w2[k2*64 + lane];
    double2 a  = x2[(nb+0)*32 + k2];
    double2 b  = x2[(nb+1)*32 + k2];
    double2 c  = x2[(nb+2)*32 + k2];
    double2 d  = x2[(nb+3)*32 + k2];
    acc0 = fma(wt.x, a.x, acc0); acc0 = fma(wt.y, a.y, acc0);
    acc1 = fma(wt.x, b.x, acc1); acc1 = fma(wt.y, b.y, acc1);
    acc2 = fma(wt.x, c.x, acc2); acc2 = fma(wt.y, c.y, acc2);
    acc3 = fma(wt.x, d.x, acc3); acc3 = fma(wt.y, d.y, acc3);
  }
  {int node=i0+nb+0; if(node<N) mx[(size_t)node*64+lane]=acc0;}
  {int node=i0+nb+1; if(node<N) mx[(size_t)node*64+lane]=acc1;}
  {int node=i0+nb+2; if(node<N) mx[(size_t)node*64+lane]=acc2;}
  {int node=i0+nb+3; if(node<N) mx[(size_t)node*64+lane]=acc3;}
}

// ---- K2: r1=|x|^2, r2=|mx|^2, r3=<mx,hb> (16 lanes/node, streaming) --------
__global__ __launch_bounds__(256) void k_reduce(
    const float* __restrict__ x, const double* __restrict__ mx,
    const double* __restrict__ hb,
    double* __restrict__ r1, double* __restrict__ r2, double* __restrict__ r3,
    int N){
  int lane = threadIdx.x & 63;
  int wid  = (int)((blockIdx.x*(unsigned)blockDim.x + threadIdx.x)>>6);
  int g = lane>>4, t = lane&15;
  int i = wid*4 + g;
  if(i>=N) return;
  size_t b = (size_t)i*64 + t*4;
  float4  xv = *(const float4*)(x+b);
  double2 m0 = *(const double2*)(mx+b);
  double2 m1 = *(const double2*)(mx+b+2);
  double2 h0 = *(const double2*)(hb+t*4);
  double2 h1 = *(const double2*)(hb+t*4+2);
  double s1 = qsumd((double)xv.x*xv.x + (double)xv.y*xv.y
                  + (double)xv.z*xv.z + (double)xv.w*xv.w);
  double s2 = qsumd(m0.x*m0.x + m0.y*m0.y + m1.x*m1.x + m1.y*m1.y);
  double s3 = qsumd(m0.x*h0.x + m0.y*h0.y + m1.x*h1.x + m1.y*h1.y);
  if(t==0){ r1[i]=s1; r2[i]=s2; r3[i]=s3; }
}

// ---- K3: per-node scalar chain (one THREAD per node) -> alpha, beta --------
__global__ void k_chain(const double* __restrict__ r1, const double* __restrict__ r2,
                        const double* __restrict__ r3, const double* __restrict__ hb2p,
                        double* __restrict__ alpha, double* __restrict__ beta, int N){
  int i = blockIdx.x*blockDim.x + threadIdx.x;
  if(i>=N) return;
  double x2s = r1[i], m2 = r2[i], mh = r3[i];
  double y2 = *hb2p;
  double xn  = fmax(sqrt(x2s), 1e-15);
  double mxn = fmax(sqrt(m2), 1e-15);
  double xc  = fmin(fmax(xn, -1.0+1e-7), 1.0-1e-7);
  double at  = 0.5*(log1p(xc)-log1p(-xc));        // artanh(|x|)
  double f1  = tanh(mxn/xn*at)/mxn;               // h = f1*mx
  if(m2 == 0.0) f1 = 0.0;
  double h2 = f1*f1*m2;
  double hn = fmax(sqrt(h2), 1e-15);
  if(hn > MAXN_D){ double s = MAXN_D/hn; f1 *= s; h2 = f1*f1*m2; }   // proj(h)
  double xy = f1*mh;
  double den = fmax(1.0 + 2.0*xy + h2*y2, 1e-15);
  double a = (1.0 + 2.0*xy + y2)/den;
  double b = (1.0 - h2)/den;
  double p2 = a*a*h2 + 2.0*a*b*xy + b*b*y2;
  double pn = fmax(sqrt(p2), 1e-15);
  if(pn > MAXN_D){ double s = MAXN_D/pn; a*=s; b*=s; pn = fmax(pn*s, 1e-15); }
  double nc  = fmin(fmax(pn, -1.0+1e-7), 1.0-1e-7);
  double at2 = 0.5*(log1p(nc)-log1p(-nc));        // artanh(|p|)
  double sc  = at2/pn;                            // logmap0 scale
  alpha[i] = sc*a*f1;
  beta[i]  = sc*b;
}

// ---- K4: x_tan = alpha*mx + beta*hb (double2 streaming) --------------------
__global__ void k_apply(const double* __restrict__ mx, const double* __restrict__ alpha,
                        const double* __restrict__ beta, const double* __restrict__ hb,
                        double* __restrict__ xtd, float* __restrict__ xtf, int N){
  size_t idx = ((size_t)blockIdx.x*blockDim.x + threadIdx.x)*2;
  if(idx >= (size_t)N*64) return;
  int i = (int)(idx>>6);
  double al = alpha[i], be = beta[i];
  double2 m  = *(const double2*)(mx+idx);
  double2 hv = *(const double2*)(hb+(idx&63));
  double2 v; v.x = al*m.x + be*hv.x; v.y = al*m.y + be*hv.y;
  *(double2*)(xtd+idx) = v;
  float2 f; f.x = (float)v.x; f.y = (float)v.y;
  *(float2*)(xtf+idx) = f;
}

// ---- K5: bin count: per-block LDS hist of dst>>8 and src>>8 (s!=d) ---------
__global__ __launch_bounds__(256) void k_binCount(const int* __restrict__ ei, int E,
    int NB, int chunk, int* __restrict__ dstTot, int* __restrict__ srcTot){
  __shared__ int dh[NBMAX], sh_[NBMAX];
  for(int t=threadIdx.x; t<NB; t+=256){ dh[t]=0; sh_[t]=0; }
  __syncthreads();
  int start = blockIdx.x*chunk, end = min(E, start+chunk);
  for(int e=start+(int)threadIdx.x; e<end; e+=256){
    int s = ei[e], d = ei[(size_t)E+e];
    atomicAdd(&dh[d>>8],1);
    if(s!=d) atomicAdd(&sh_[s>>8],1);
  }
  __syncthreads();
  for(int t=threadIdx.x; t<NB; t+=256){
    if(dh[t])  atomicAdd(&dstTot[t], dh[t]);
    if(sh_[t]) atomicAdd(&srcTot[t], sh_[t]);
  }
}

// ---- K6: small scans: bucket totals -> bases + cursors; rowptr[N]=E --------
__global__ __launch_bounds__(NBMAX) void k_smallScan(
    const int* __restrict__ dstTot, const int* __restrict__ srcTot, int NB,
    int* __restrict__ dstBase, int* __restrict__ dstCur,
    int* __restrict__ srcBase, int* __restrict__ srcCur,
    int* __restrict__ rowptr, int N, int E){
  __shared__ int sh[NBMAX];
  int t = threadIdx.x;
  int v = (t<NB) ? dstTot[t] : 0;
  sh[t] = v; __syncthreads();
  for(int off=1; off<NBMAX; off<<=1){
    int a = (t>=off) ? sh[t-off] : 0; __syncthreads();
    sh[t] += a; __syncthreads();
  }
  if(t<NB){ int e = sh[t]-v; dstBase[t]=e; dstCur[t]=e; }
  __syncthreads();
  int v2 = (t<NB) ? srcTot[t] : 0;
  sh[t] = v2; __syncthreads();
  for(int off=1; off<NBMAX; off<<=1){
    int a = (t>=off) ? sh[t-off] : 0; __syncthreads();
    sh[t] += a; __syncthreads();
  }
  if(t<NB){ int e = sh[t]-v2; srcBase[t]=e; srcCur[t]=e; }
  __syncthreads();
  if(t==0){
    dstBase[NB] = E;
    srcBase[NB] = sh[NBMAX-1];   // total non-self-loop edges
    rowptr[N] = E;
  }
}

// ---- K7: bin place: reserve per-block ranges, line-dense binned writes -----
__global__ __launch_bounds__(256) void k_binPlace(const int* __restrict__ ei, int E,
    int NB, int chunk, int* __restrict__ dstCur, int* __restrict__ srcCur,
    ull* __restrict__ dstbin, int* __restrict__ srcbin){
  __shared__ int dh[NBMAX], sh_[NBMAX];
  __shared__ int db[NBMAX], sb[NBMAX];
  for(int t=threadIdx.x; t<NB; t+=256){ dh[t]=0; sh_[t]=0; }
  __syncthreads();
  int start = blockIdx.x*chunk, end = min(E, start+chunk);
  for(int e=start+(int)threadIdx.x; e<end; e+=256){
    int s = ei[e], d = ei[(size_t)E+e];
    atomicAdd(&dh[d>>8],1);
    if(s!=d) atomicAdd(&sh_[s>>8],1);
  }
  __syncthreads();
  for(int t=threadIdx.x; t<NB; t+=256){
    db[t] = dh[t]  ? atomicAdd(&dstCur[t], dh[t])  : 0;
    sb[t] = sh_[t] ? atomicAdd(&srcCur[t], sh_[t]) : 0;
  }
  __syncthreads();
  for(int t=threadIdx.x; t<NB; t+=256){ dh[t]=db[t]; sh_[t]=sb[t]; }
  __syncthreads();
  for(int e=start+(int)threadIdx.x; e<end; e+=256){
    int s = ei[e], d = ei[(size_t)E+e];
    int p = atomicAdd(&dh[d>>8],1);
    dstbin[p] = ((ull)(unsigned)d<<32) | (unsigned)s;
    if(s!=d){ int p2 = atomicAdd(&sh_[s>>8],1); srcbin[p2] = s; }
  }
}

// ---- K8: per dst-bucket: LDS count + scan -> rowptr, scatter src -> csr ----
__global__ __launch_bounds__(256) void k_bucketA(const ull* __restrict__ dstbin,
    const int* __restrict__ dstBase, int* __restrict__ rowptr,
    int* __restrict__ csr, int N){
  int b = blockIdx.x;
  int node0 = b<<8;
  int nodes = min(256, N-node0);
  int base = dstBase[b], cnt = dstBase[b+1]-base;
  __shared__ int c[256], ex[256];
  int t = threadIdx.x;
  c[t]=0; __syncthreads();
  for(int e=base+t; e<base+cnt; e+=256){
    int d = (int)(dstbin[e]>>32);
    atomicAdd(&c[d-node0],1);
  }
  __syncthreads();
  int v = c[t]; ex[t]=v; __syncthreads();
  for(int off=1; off<256; off<<=1){
    int a = (t>=off) ? ex[t-off] : 0; __syncthreads();
    ex[t] += a; __syncthreads();
  }
  int mybase = base + ex[t] - v;             // exclusive
  if(t<nodes) rowptr[node0+t] = mybase;
  c[t] = mybase;                             // reuse as cursor
  __syncthreads();
  for(int e=base+t; e<base+cnt; e+=256){
    ull pr = dstbin[e];
    int d = (int)(pr>>32);
    int p = atomicAdd(&c[d-node0],1);
    csr[p] = (int)(pr & 0xffffffffu);
  }
}

// ---- K9: per src-bucket: LDS count -> dinv dense ---------------------------
__global__ __launch_bounds__(256) void k_bucketB(const int* __restrict__ srcbin,
    const int* __restrict__ srcBase, double* __restrict__ dinv, int N){
  int b = blockIdx.x;
  int node0 = b<<8;
  int nodes = min(256, N-node0);
  int base = srcBase[b], cnt = srcBase[b+1]-base;
  __shared__ int c[256];
  int t = threadIdx.x;
  c[t]=0; __syncthreads();
  for(int e=base+t; e<base+cnt; e+=256)
    atomicAdd(&c[srcbin[e]-node0],1);
  __syncthreads();
  if(t<nodes){ int d = c[t]; dinv[node0+t] = (d>0) ? 1.0/sqrt((double)d) : 0.0; }
}

// ---- K10: gather A: info score key (f64 accum over f32 rows) ---------------
__global__ void k_gatherA(const int* __restrict__ csr, const int* __restrict__ rowptr,
                          const float* __restrict__ xtf, const double* __restrict__ xtd,
                          const double* __restrict__ dinv,
                          ull* __restrict__ keys, int N){
  int lane = threadIdx.x & 63;
  int i = (int)((blockIdx.x*(unsigned)blockDim.x + threadIdx.x)>>6);
  if(i>=N) return;
  int beg = rowptr[i], deg = rowptr[i+1]-beg;
  int g = lane>>4, t = lane&15;
  double di = dinv[i];
  double a0=0.0,a1=0.0,a2=0.0,a3=0.0;
  int j = g;
  int s = (j<deg) ? csr[beg+j] : 0;
  while(j < deg){
    int snext = (j+4<deg) ? csr[beg+j+4] : 0;
    if(s != i){
      double w = di*dinv[s];
      float4 v = *((const float4*)(xtf + (size_t)s*64 + t*4));
      a0 -= w*(double)v.x; a1 -= w*(double)v.y;
      a2 -= w*(double)v.z; a3 -= w*(double)v.w;
    }
    s = snext; j += 4;
  }
  a0 = gsumd(a0); a1 = gsumd(a1); a2 = gsumd(a2); a3 = gsumd(a3);
  const double2* xr = (const double2*)(xtd + (size_t)i*64 + t*4);
  double2 x0 = xr[0], x1 = xr[1];
  double sc = fabs(x0.x+a0) + fabs(x0.y+a1) + fabs(x1.x+a2) + fabs(x1.y+a3);
  sc = qsumd(sc);
  if(lane==0) keys[i] = (ull)__double_as_longlong(sc);
}

// ---- K11: fused radix level: grid hist + last-block pick (ticket) ----------
__global__ void k_histpick(const ull* __restrict__ keys, int N,
                           ull* __restrict__ pref, int* __restrict__ rem,
                           int lev, int* __restrict__ hist, int* __restrict__ ticket){
  __shared__ int h[256];
  __shared__ int lastflag;
  h[threadIdx.x] = 0;
  __syncthreads();
  int shift = 56 - 8*lev;
  ull p = *pref;
  for(int i = blockIdx.x*blockDim.x + threadIdx.x; i<N; i += gridDim.x*blockDim.x){
    ull kk = keys[i];
    if(lev==0 || (kk >> (shift+8)) == (p >> (shift+8)))
      atomicAdd(&h[(int)((kk>>shift)&255)], 1);
  }
  __syncthreads();
  if(h[threadIdx.x])
    __hip_atomic_fetch_add(&hist[threadIdx.x], h[threadIdx.x],
                           __ATOMIC_RELAXED, __HIP_MEMORY_SCOPE_AGENT);
  __threadfence();
  if(threadIdx.x==0){
    int tk = __hip_atomic_fetch_add(ticket, 1, __ATOMIC_ACQ_REL, __HIP_MEMORY_SCOPE_AGENT);
    lastflag = (tk == (int)gridDim.x - 1);
  }
  __syncthreads();
  if(!lastflag) return;
  int v = __hip_atomic_load(&hist[threadIdx.x], __ATOMIC_RELAXED, __HIP_MEMORY_SCOPE_AGENT);
  h[threadIdx.x] = v;
  __syncthreads();
  if(threadIdx.x==0){
    int r = *rem, cum = 0, chosen = 0;
    for(int d=255; d>=0; --d){
      cum += h[d];
      if(cum >= r){ chosen = d; r -= (cum - h[d]); break; }
    }
    *rem = r;
    *pref = p | ((ull)chosen << shift);
  }
}

// ---- K12: gather C + gate: sum_neigh AND sum_sel in one sweep --------------
__global__ void k_gatherC(const int* __restrict__ csr, const int* __restrict__ rowptr,
                          const float* __restrict__ xtf,
                          const ull* __restrict__ keys, const ull* __restrict__ keyT,
                          const float* __restrict__ lww, const float* __restrict__ lwb,
                          float* __restrict__ gate, int N){
  ull T = *keyT;
  int lane = threadIdx.x & 63;
  int i = (int)((blockIdx.x*(unsigned)blockDim.x + threadIdx.x)>>6);
  if(i>=N) return;
  int beg = rowptr[i], deg = rowptr[i+1]-beg;
  int g = lane>>4, t = lane&15;
  float c0=0.f,c1=0.f,c2=0.f,c3=0.f;
  float n0=0.f,n1=0.f,n2=0.f,n3=0.f;
  int j = g;
  int s = (j<deg) ? csr[beg+j] : 0;
  while(j < deg){
    int snext = (j+4<deg) ? csr[beg+j+4] : 0;
    float4 v = *((const float4*)(xtf + (size_t)s*64 + t*4));
    n0 += v.x; n1 += v.y; n2 += v.z; n3 += v.w;
    if(keys[s] > T){ c0 += v.x; c1 += v.y; c2 += v.z; c3 += v.w; }
    s = snext; j += 4;
  }
  c0 = gsumf(c0); c1 = gsumf(c1); c2 = gsumf(c2); c3 = gsumf(c3);
  n0 = gsumf(n0); n1 = gsumf(n1); n2 = gsumf(n2); n3 = gsumf(n3);
  float4 wA = *((const float4*)(lww + t*4));
  float4 wB = *((const float4*)(lww + 64 + t*4));
  float z = c0*wA.x + c1*wA.y + c2*wA.z + c3*wA.w
          + n0*wB.x + n1*wB.y + n2*wB.z + n3*wB.w;
  z = qsumf(z);
  if(lane==0) gate[i] = 1.f/(1.f+expf(-(z+lwb[0])));
}

// ---- K13: gather D + final chain -------------------------------------------
__global__ void k_gatherD(const int* __restrict__ csr, const int* __restrict__ rowptr,
                          const float* __restrict__ xtf,
                          const ull* __restrict__ keys, const ull* __restrict__ keyT,
                          const float* __restrict__ gate,
                          float* __restrict__ out, int N){
  ull T = *keyT;
  int lane = threadIdx.x & 63;
  int i = (int)((blockIdx.x*(unsigned)blockDim.x + threadIdx.x)>>6);
  if(i>=N) return;
  int beg = rowptr[i], deg = rowptr[i+1]-beg;
  int g = lane>>4, t = lane&15;
  float c0=0.f,c1=0.f,c2=0.f,c3=0.f;
  int j = g;
  int s = (j<deg) ? csr[beg+j] : 0;
  while(j < deg){
    int snext = (j+4<deg) ? csr[beg+j+4] : 0;
    if(keys[s] > T){
      float gv = gate[s];
      float4 v = *((const float4*)(xtf + (size_t)s*64 + t*4));
      c0 = fmaf(gv, v.x, c0); c1 = fmaf(gv, v.y, c1);
      c2 = fmaf(gv, v.z, c2); c3 = fmaf(gv, v.w, c3);
    }
    s = snext; j += 4;
  }
  c0 = gsumf(c0); c1 = gsumf(c1); c2 = gsumf(c2); c3 = gsumf(c3);
  float4 xr = *((const float4*)(xtf + (size_t)i*64 + t*4));
  float v0 = xr.x + fmaxf(c0,0.f);
  float v1 = xr.y + fmaxf(c1,0.f);
  float v2 = xr.z + fmaxf(c2,0.f);
  float v3 = xr.w + fmaxf(c3,0.f);
  float n2 = qsumf(v0*v0 + v1*v1 + v2*v2 + v3*v3);
  float n = fmaxf(sqrtf(n2), 1e-15f);
  float f = tanhf(n)/n;
  float e0=f*v0, e1=f*v1, e2=f*v2, e3=f*v3;
  float en = fmaxf(tanhf(n), 1e-15f);
  if(en > MAXN_F){ float sf = MAXN_F/en; e0*=sf; e1*=sf; e2*=sf; e3*=sf; }
  e0 = fmaxf(e0,0.f); e1 = fmaxf(e1,0.f); e2 = fmaxf(e2,0.f); e3 = fmaxf(e3,0.f);
  float m2 = qsumf(e0*e0 + e1*e1 + e2*e2 + e3*e3);
  float nb = fmaxf(sqrtf(m2), 1e-15f);
  float f2 = tanhf(nb)/nb;
  float o0=f2*e0, o1=f2*e1, o2=f2*e2, o3=f2*e3;
  float on = fmaxf(tanhf(nb), 1e-15f);
  if(on > MAXN_F){ float sf = MAXN_F/on; o0*=sf; o1*=sf; o2*=sf; o3*=sf; }
  if(g==0){
    float4 ov = make_float4(o0,o1,o2,o3);
    *((float4*)(out + (size_t)i*64 + t*4)) = ov;
  }
}

// ---------------------------------------------------------------------------
extern "C" void kernel_launch(void* const* d_in, const int* in_sizes, int n_in,
                              void* d_out, int out_size, void* d_ws, size_t ws_size,
                              hipStream_t stream){
  const float* x    = (const float*)d_in[0];
  const int*   ei   = (const int*)d_in[1];
  const float* W    = (const float*)d_in[2];
  const float* bias = (const float*)d_in[3];
  const float* lww  = (const float*)d_in[4];
  const float* lwb  = (const float*)d_in[5];
  int N = in_sizes[0]/64;
  int E = in_sizes[1]/2;
  int kth = (int)((double)N*0.75);
  int NB = (N+255)>>8;                         // node buckets (256 nodes each)
  if(NB > NBMAX) return;                       // loud failure if N too large
  int chunk = (E + BINBLK - 1)/BINBLK;

  char* ws = (char*)d_ws;
  size_t cur = 0;
  auto alloc = [&](size_t bytes){ size_t o = cur; cur = (cur + bytes + 255) & ~(size_t)255; return o; };
  size_t o_hb   = alloc(64*sizeof(double));
  size_t o_hb2  = alloc(8);
  size_t o_keyT = alloc(8);
  size_t o_rem  = alloc(4);
  size_t o_zero = cur;                         // ---- zeroed region start ----
  size_t o_hist = alloc(8*256*4);              // per-level hist
  size_t o_tick = alloc(8*4);                  // per-level tickets
  size_t o_dTot = alloc((size_t)NBMAX*4);
  size_t o_sTot = alloc((size_t)NBMAX*4);
  size_t zlen   = cur - o_zero;                // ---- zeroed region end ------
  size_t o_dBas = alloc((size_t)(NBMAX+1)*4);
  size_t o_sBas = alloc((size_t)(NBMAX+1)*4);
  size_t o_dCur = alloc((size_t)NBMAX*4);
  size_t o_sCur = alloc((size_t)NBMAX*4);
  size_t o_rowp = alloc((size_t)(N+1)*4);
  size_t o_csr  = alloc((size_t)E*4);
  size_t o_dbin = alloc((size_t)E*8);
  size_t o_sbin = alloc((size_t)E*4);
  size_t o_dinv = alloc((size_t)N*8);
  size_t o_keys = alloc((size_t)N*8);
  size_t o_xtf  = alloc((size_t)N*64*4);
  size_t o_xtd  = alloc((size_t)N*64*8);
  size_t o_mx   = alloc((size_t)N*64*8);
  size_t o_r1   = alloc((size_t)N*8);
  size_t o_r2   = alloc((size_t)N*8);
  size_t o_r3   = alloc((size_t)N*8);
  size_t o_al   = alloc((size_t)N*8);
  size_t o_be   = alloc((size_t)N*8);
  size_t o_gate = alloc((size_t)N*4);
  if(ws_size < cur) return;                    // loud, clean failure

  double* hb     = (double*)(ws+o_hb);
  double* hb2    = (double*)(ws+o_hb2);
  ull*    keyT   = (ull*)(ws+o_keyT);
  int*    rem    = (int*)(ws+o_rem);
  int*    hist   = (int*)(ws+o_hist);
  int*    tick   = (int*)(ws+o_tick);
  int*    dstTot = (int*)(ws+o_dTot);
  int*    srcTot = (int*)(ws+o_sTot);
  int*    dstBase= (int*)(ws+o_dBas);
  int*    srcBase= (int*)(ws+o_sBas);
  int*    dstCur = (int*)(ws+o_dCur);
  int*    srcCur = (int*)(ws+o_sCur);
  int*    rowptr = (int*)(ws+o_rowp);
  int*    csr    = (int*)(ws+o_csr);
  ull*    dstbin = (ull*)(ws+o_dbin);
  int*    srcbin = (int*)(ws+o_sbin);
  double* dinv   = (double*)(ws+o_dinv);
  ull*    keys   = (ull*)(ws+o_keys);
  float*  xtf    = (float*)(ws+o_xtf);
  double* xtd    = (double*)(ws+o_xtd);
  double* mx     = (double*)(ws+o_mx);
  double* r1     = (double*)(ws+o_r1);
  double* r2     = (double*)(ws+o_r2);
  double* r3     = (double*)(ws+o_r3);
  double* alpha  = (double*)(ws+o_al);
  double* beta   = (double*)(ws+o_be);
  float*  gate   = (float*)(ws+o_gate);

  hipMemsetAsync(ws+o_zero, 0, zlen, stream);

  int nodeBlocks = (N+3)/4;                    // 1 wave per node
  int rBlocks    = (N+15)/16;                  // 4 nodes per wave (k_reduce)
  k_init     <<<1, 64, 0, stream>>>(bias, hb, hb2, keyT, rem, kth);
  k_gemm     <<<(N+NPB-1)/NPB, 256, 0, stream>>>(x, W, mx, N);
  k_reduce   <<<rBlocks, 256, 0, stream>>>(x, mx, hb, r1, r2, r3, N);
  k_chain    <<<(N+255)/256, 256, 0, stream>>>(r1, r2, r3, hb2, alpha, beta, N);
  k_apply    <<<(N*32+255)/256, 256, 0, stream>>>(mx, alpha, beta, hb, xtd, xtf, N);
  k_binCount <<<BINBLK, 256, 0, stream>>>(ei, E, NB, chunk, dstTot, srcTot);
  k_smallScan<<<1, NBMAX, 0, stream>>>(dstTot, srcTot, NB, dstBase, dstCur,
                                       srcBase, srcCur, rowptr, N, E);
  k_binPlace <<<BINBLK, 256, 0, stream>>>(ei, E, NB, chunk, dstCur, srcCur, dstbin, srcbin);
  k_bucketA  <<<NB, 256, 0, stream>>>(dstbin, dstBase, rowptr, csr, N);
  k_bucketB  <<<NB, 256, 0, stream>>>(srcbin, srcBase, dinv, N);
  k_gatherA  <<<nodeBlocks, 256, 0, stream>>>(csr, rowptr, xtf, xtd, dinv, keys, N);
  for(int lev=0; lev<8; ++lev)
    k_histpick<<<256, 256, 0, stream>>>(keys, N, keyT, rem, lev, hist+lev*256, tick+lev);
  k_gatherC  <<<nodeBlocks, 256, 0, stream>>>(csr, rowptr, xtf, keys, keyT, lww, lwb, gate, N);
  k_gatherD  <<<nodeBlocks, 256, 0, stream>>>(csr, rowptr, xtf, keys, keyT, gate, (float*)d_out, N);
}

// Round 9
// 526.190 us; speedup vs baseline: 1.8988x; 1.0825x over previous
//
#include <hip/hip_runtime.h>
#include <math.h>

// ---------------------------------------------------------------------------
// HyperbolicGraphConvolution (HGCN HypLinear + NodeSelect + HypAct), c=1.
// Round 9: gate-path scalarization. gatherC's row gathers collapse to a 4B
// q[s] gather per edge: q[s] = xtf[s]·wB + sel[s]*(xtf[s]·wA); pA/pB computed
// in gatherA's epilogue (row already in regs). sel folded into gate (gg) so
// gatherD drops the keys gather. Select/keys path bit-identical to round 8.
// ---------------------------------------------------------------------------

#define MAXN_D 0.996      // (1 - 4e-3)/sqrt(c), c=1
#define MAXN_F 0.996f
#define NPB 16            // nodes per block in k_gemm
#define NBMAX 512         // max buckets (N <= 131072)
#define BINBLK 256        // blocks in bin kernels

typedef unsigned long long ull;

__device__ __forceinline__ double wsumd(double v){
#pragma unroll
  for(int o=32;o;o>>=1) v += __shfl_xor(v,o,64);
  return v;
}
__device__ __forceinline__ double qsumd(double v){
#pragma unroll
  for(int o=1;o<16;o<<=1) v += __shfl_xor(v,o,64);
  return v;
}
__device__ __forceinline__ float qsumf(float v){
#pragma unroll
  for(int o=1;o<16;o<<=1) v += __shfl_xor(v,o,64);
  return v;
}
__device__ __forceinline__ double gsumd(double v){
  v += __shfl_xor(v,16,64); v += __shfl_xor(v,32,64); return v;
}
__device__ __forceinline__ float gsumf(float v){
  v += __shfl_xor(v,16,64); v += __shfl_xor(v,32,64); return v;
}

// ---- K0: hyp_bias (double) + |hb|^2 + init select state --------------------
__global__ void k_init(const float* __restrict__ bias, double* __restrict__ hb,
                       double* __restrict__ hb2, ull* __restrict__ pref,
                       int* __restrict__ rem, int kth){
  if(threadIdx.x < 64){
    int lane = threadIdx.x;
    double b = (double)bias[lane];
    double n = fmax(sqrt(wsumd(b*b)), 1e-15);
    double e = tanh(n)*b/n;                       // expmap0, sc=1
    double en = fmax(sqrt(wsumd(e*e)), 1e-15);
    if(en > MAXN_D) e *= MAXN_D/en;               // proj
    hb[lane] = e;
    double s2 = wsumd(e*e);
    if(lane==0) *hb2 = s2;
  }
  if(threadIdx.x == 0){ *pref = 0ull; *rem = kth; }
}

// ---- K1: mx = x @ W^T (f64, LDS-tiled, pure) -------------------------------
__global__ __launch_bounds__(256) void k_gemm(
    const float* __restrict__ x, const float* __restrict__ W,
    double* __restrict__ mx, int N){
  __shared__ double wlds[4096];     // double2 [k2][j]: flat (k>>1)*128 + j*2 + (k&1)
  __shared__ double xlds[NPB*64];   // [n][k] f64
  int tid = threadIdx.x;
  for(int idx=tid; idx<4096; idx+=256){
    int j = idx>>6, k = idx&63;
    wlds[(k>>1)*128 + j*2 + (k&1)] = (double)W[idx];
  }
  int i0 = blockIdx.x*NPB;
  for(int idx=tid; idx<NPB*64; idx+=256){
    int node = i0 + (idx>>6);
    xlds[idx] = (node<N) ? (double)x[(size_t)node*64 + (idx&63)] : 0.0;
  }
  __syncthreads();
  int lane = tid & 63;
  int nb = (tid>>6)*4;
  double acc0=0.0, acc1=0.0, acc2=0.0, acc3=0.0;
  const double2* w2 = (const double2*)wlds;
  const double2* x2 = (const double2*)xlds;
#pragma unroll 4
  for(int k2=0; k2<32; ++k2){
    double2 wt = w2[k2*64 + lane];
    double2 a  = x2[(nb+0)*32 + k2];
    double2 b  = x2[(nb+1)*32 + k2];
    double2 c  = x2[(nb+2)*32 + k2];
    double2 d  = x2[(nb+3)*32 + k2];
    acc0 = fma(wt.x, a.x, acc0); acc0 = fma(wt.y, a.y, acc0);
    acc1 = fma(wt.x, b.x, acc1); acc1 = fma(wt.y, b.y, acc1);
    acc2 = fma(wt.x, c.x, acc2); acc2 = fma(wt.y, c.y, acc2);
    acc3 = fma(wt.x, d.x, acc3); acc3 = fma(wt.y, d.y, acc3);
  }
  {int node=i0+nb+0; if(node<N) mx[(size_t)node*64+lane]=acc0;}
  {int node=i0+nb+1; if(node<N) mx[(size_t)node*64+lane]=acc1;}
  {int node=i0+nb+2; if(node<N) mx[(size_t)node*64+lane]=acc2;}
  {int node=i0+nb+3; if(node<N) mx[(size_t)node*64+lane]=acc3;}
}

// ---- K2: r1=|x|^2, r2=|mx|^2, r3=<mx,hb> (16 lanes/node, streaming) --------
__global__ __launch_bounds__(256) void k_reduce(
    const float* __restrict__ x, const double* __restrict__ mx,
    const double* __restrict__ hb,
    double* __restrict__ r1, double* __restrict__ r2, double* __restrict__ r3,
    int N){
  int lane = threadIdx.x & 63;
  int wid  = (int)((blockIdx.x*(unsigned)blockDim.x + threadIdx.x)>>6);
  int g = lane>>4, t = lane&15;
  int i = wid*4 + g;
  if(i>=N) return;
  size_t b = (size_t)i*64 + t*4;
  float4  xv = *(const float4*)(x+b);
  double2 m0 = *(const double2*)(mx+b);
  double2 m1 = *(const double2*)(mx+b+2);
  double2 h0 = *(const double2*)(hb+t*4);
  double2 h1 = *(const double2*)(hb+t*4+2);
  double s1 = qsumd((double)xv.x*xv.x + (double)xv.y*xv.y
                  + (double)xv.z*xv.z + (double)xv.w*xv.w);
  double s2 = qsumd(m0.x*m0.x + m0.y*m0.y + m1.x*m1.x + m1.y*m1.y);
  double s3 = qsumd(m0.x*h0.x + m0.y*h0.y + m1.x*h1.x + m1.y*h1.y);
  if(t==0){ r1[i]=s1; r2[i]=s2; r3[i]=s3; }
}

// ---- K3: per-node scalar chain (one THREAD per node) -> alpha, beta --------
__global__ void k_chain(const double* __restrict__ r1, const double* __restrict__ r2,
                        const double* __restrict__ r3, const double* __restrict__ hb2p,
                        double* __restrict__ alpha, double* __restrict__ beta, int N){
  int i = blockIdx.x*blockDim.x + threadIdx.x;
  if(i>=N) return;
  double x2s = r1[i], m2 = r2[i], mh = r3[i];
  double y2 = *hb2p;
  double xn  = fmax(sqrt(x2s), 1e-15);
  double mxn = fmax(sqrt(m2), 1e-15);
  double xc  = fmin(fmax(xn, -1.0+1e-7), 1.0-1e-7);
  double at  = 0.5*(log1p(xc)-log1p(-xc));        // artanh(|x|)
  double f1  = tanh(mxn/xn*at)/mxn;               // h = f1*mx
  if(m2 == 0.0) f1 = 0.0;
  double h2 = f1*f1*m2;
  double hn = fmax(sqrt(h2), 1e-15);
  if(hn > MAXN_D){ double s = MAXN_D/hn; f1 *= s; h2 = f1*f1*m2; }   // proj(h)
  double xy = f1*mh;
  double den = fmax(1.0 + 2.0*xy + h2*y2, 1e-15);
  double a = (1.0 + 2.0*xy + y2)/den;
  double b = (1.0 - h2)/den;
  double p2 = a*a*h2 + 2.0*a*b*xy + b*b*y2;
  double pn = fmax(sqrt(p2), 1e-15);
  if(pn > MAXN_D){ double s = MAXN_D/pn; a*=s; b*=s; pn = fmax(pn*s, 1e-15); }
  double nc  = fmin(fmax(pn, -1.0+1e-7), 1.0-1e-7);
  double at2 = 0.5*(log1p(nc)-log1p(-nc));        // artanh(|p|)
  double sc  = at2/pn;                            // logmap0 scale
  alpha[i] = sc*a*f1;
  beta[i]  = sc*b;
}

// ---- K4: x_tan = alpha*mx + beta*hb (double2 streaming) --------------------
__global__ void k_apply(const double* __restrict__ mx, const double* __restrict__ alpha,
                        const double* __restrict__ beta, const double* __restrict__ hb,
                        double* __restrict__ xtd, float* __restrict__ xtf, int N){
  size_t idx = ((size_t)blockIdx.x*blockDim.x + threadIdx.x)*2;
  if(idx >= (size_t)N*64) return;
  int i = (int)(idx>>6);
  double al = alpha[i], be = beta[i];
  double2 m  = *(const double2*)(mx+idx);
  double2 hv = *(const double2*)(hb+(idx&63));
  double2 v; v.x = al*m.x + be*hv.x; v.y = al*m.y + be*hv.y;
  *(double2*)(xtd+idx) = v;
  float2 f; f.x = (float)v.x; f.y = (float)v.y;
  *(float2*)(xtf+idx) = f;
}

// ---- K5: bin count: per-block LDS hist of dst>>8 and src>>8 (s!=d) ---------
__global__ __launch_bounds__(256) void k_binCount(const int* __restrict__ ei, int E,
    int NB, int chunk, int* __restrict__ dstTot, int* __restrict__ srcTot){
  __shared__ int dh[NBMAX], sh_[NBMAX];
  for(int t=threadIdx.x; t<NB; t+=256){ dh[t]=0; sh_[t]=0; }
  __syncthreads();
  int start = blockIdx.x*chunk, end = min(E, start+chunk);
  for(int e=start+(int)threadIdx.x; e<end; e+=256){
    int s = ei[e], d = ei[(size_t)E+e];
    atomicAdd(&dh[d>>8],1);
    if(s!=d) atomicAdd(&sh_[s>>8],1);
  }
  __syncthreads();
  for(int t=threadIdx.x; t<NB; t+=256){
    if(dh[t])  atomicAdd(&dstTot[t], dh[t]);
    if(sh_[t]) atomicAdd(&srcTot[t], sh_[t]);
  }
}

// ---- K6: small scans: bucket totals -> bases + cursors; rowptr[N]=E --------
__global__ __launch_bounds__(NBMAX) void k_smallScan(
    const int* __restrict__ dstTot, const int* __restrict__ srcTot, int NB,
    int* __restrict__ dstBase, int* __restrict__ dstCur,
    int* __restrict__ srcBase, int* __restrict__ srcCur,
    int* __restrict__ rowptr, int N, int E){
  __shared__ int sh[NBMAX];
  int t = threadIdx.x;
  int v = (t<NB) ? dstTot[t] : 0;
  sh[t] = v; __syncthreads();
  for(int off=1; off<NBMAX; off<<=1){
    int a = (t>=off) ? sh[t-off] : 0; __syncthreads();
    sh[t] += a; __syncthreads();
  }
  if(t<NB){ int e = sh[t]-v; dstBase[t]=e; dstCur[t]=e; }
  __syncthreads();
  int v2 = (t<NB) ? srcTot[t] : 0;
  sh[t] = v2; __syncthreads();
  for(int off=1; off<NBMAX; off<<=1){
    int a = (t>=off) ? sh[t-off] : 0; __syncthreads();
    sh[t] += a; __syncthreads();
  }
  if(t<NB){ int e = sh[t]-v2; srcBase[t]=e; srcCur[t]=e; }
  __syncthreads();
  if(t==0){
    dstBase[NB] = E;
    srcBase[NB] = sh[NBMAX-1];   // total non-self-loop edges
    rowptr[N] = E;
  }
}

// ---- K7: bin place: reserve per-block ranges, line-dense binned writes -----
__global__ __launch_bounds__(256) void k_binPlace(const int* __restrict__ ei, int E,
    int NB, int chunk, int* __restrict__ dstCur, int* __restrict__ srcCur,
    ull* __restrict__ dstbin, int* __restrict__ srcbin){
  __shared__ int dh[NBMAX], sh_[NBMAX];
  __shared__ int db[NBMAX], sb[NBMAX];
  for(int t=threadIdx.x; t<NB; t+=256){ dh[t]=0; sh_[t]=0; }
  __syncthreads();
  int start = blockIdx.x*chunk, end = min(E, start+chunk);
  for(int e=start+(int)threadIdx.x; e<end; e+=256){
    int s = ei[e], d = ei[(size_t)E+e];
    atomicAdd(&dh[d>>8],1);
    if(s!=d) atomicAdd(&sh_[s>>8],1);
  }
  __syncthreads();
  for(int t=threadIdx.x; t<NB; t+=256){
    db[t] = dh[t]  ? atomicAdd(&dstCur[t], dh[t])  : 0;
    sb[t] = sh_[t] ? atomicAdd(&srcCur[t], sh_[t]) : 0;
  }
  __syncthreads();
  for(int t=threadIdx.x; t<NB; t+=256){ dh[t]=db[t]; sh_[t]=sb[t]; }
  __syncthreads();
  for(int e=start+(int)threadIdx.x; e<end; e+=256){
    int s = ei[e], d = ei[(size_t)E+e];
    int p = atomicAdd(&dh[d>>8],1);
    dstbin[p] = ((ull)(unsigned)d<<32) | (unsigned)s;
    if(s!=d){ int p2 = atomicAdd(&sh_[s>>8],1); srcbin[p2] = s; }
  }
}

// ---- K8: per dst-bucket: LDS count + scan -> rowptr, scatter src -> csr ----
__global__ __launch_bounds__(256) void k_bucketA(const ull* __restrict__ dstbin,
    const int* __restrict__ dstBase, int* __restrict__ rowptr,
    int* __restrict__ csr, int N){
  int b = blockIdx.x;
  int node0 = b<<8;
  int nodes = min(256, N-node0);
  int base = dstBase[b], cnt = dstBase[b+1]-base;
  __shared__ int c[256], ex[256];
  int t = threadIdx.x;
  c[t]=0; __syncthreads();
  for(int e=base+t; e<base+cnt; e+=256){
    int d = (int)(dstbin[e]>>32);
    atomicAdd(&c[d-node0],1);
  }
  __syncthreads();
  int v = c[t]; ex[t]=v; __syncthreads();
  for(int off=1; off<256; off<<=1){
    int a = (t>=off) ? ex[t-off] : 0; __syncthreads();
    ex[t] += a; __syncthreads();
  }
  int mybase = base + ex[t] - v;             // exclusive
  if(t<nodes) rowptr[node0+t] = mybase;
  c[t] = mybase;                             // reuse as cursor
  __syncthreads();
  for(int e=base+t; e<base+cnt; e+=256){
    ull pr = dstbin[e];
    int d = (int)(pr>>32);
    int p = atomicAdd(&c[d-node0],1);
    csr[p] = (int)(pr & 0xffffffffu);
  }
}

// ---- K9: per src-bucket: LDS count -> dinv dense ---------------------------
__global__ __launch_bounds__(256) void k_bucketB(const int* __restrict__ srcbin,
    const int* __restrict__ srcBase, double* __restrict__ dinv, int N){
  int b = blockIdx.x;
  int node0 = b<<8;
  int nodes = min(256, N-node0);
  int base = srcBase[b], cnt = srcBase[b+1]-base;
  __shared__ int c[256];
  int t = threadIdx.x;
  c[t]=0; __syncthreads();
  for(int e=base+t; e<base+cnt; e+=256)
    atomicAdd(&c[srcbin[e]-node0],1);
  __syncthreads();
  if(t<nodes){ int d = c[t]; dinv[node0+t] = (d>0) ? 1.0/sqrt((double)d) : 0.0; }
}

// ---- K10: gather A: score key (f64) + pA/pB gate dots (f32) ----------------
__global__ void k_gatherA(const int* __restrict__ csr, const int* __restrict__ rowptr,
                          const float* __restrict__ xtf, const double* __restrict__ xtd,
                          const double* __restrict__ dinv, const float* __restrict__ lww,
                          ull* __restrict__ keys, float2* __restrict__ pab, int N){
  int lane = threadIdx.x & 63;
  int i = (int)((blockIdx.x*(unsigned)blockDim.x + threadIdx.x)>>6);
  if(i>=N) return;
  int beg = rowptr[i], deg = rowptr[i+1]-beg;
  int g = lane>>4, t = lane&15;
  double di = dinv[i];
  double a0=0.0,a1=0.0,a2=0.0,a3=0.0;
  int j = g;
  int s = (j<deg) ? csr[beg+j] : 0;
  while(j < deg){
    int snext = (j+4<deg) ? csr[beg+j+4] : 0;
    if(s != i){
      double w = di*dinv[s];
      float4 v = *((const float4*)(xtf + (size_t)s*64 + t*4));
      a0 -= w*(double)v.x; a1 -= w*(double)v.y;
      a2 -= w*(double)v.z; a3 -= w*(double)v.w;
    }
    s = snext; j += 4;
  }
  a0 = gsumd(a0); a1 = gsumd(a1); a2 = gsumd(a2); a3 = gsumd(a3);
  const double2* xr = (const double2*)(xtd + (size_t)i*64 + t*4);
  double2 x0 = xr[0], x1 = xr[1];
  double sc = fabs(x0.x+a0) + fabs(x0.y+a1) + fabs(x1.x+a2) + fabs(x1.y+a3);
  sc = qsumd(sc);
  // gate dot products: pA = xtf[i]·lww[0:64], pB = xtf[i]·lww[64:128]
  float4 wA = *((const float4*)(lww + t*4));
  float4 wB = *((const float4*)(lww + 64 + t*4));
  float f0=(float)x0.x, f1v=(float)x0.y, f2v=(float)x1.x, f3=(float)x1.y;
  float pA = qsumf(f0*wA.x + f1v*wA.y + f2v*wA.z + f3*wA.w);
  float pB = qsumf(f0*wB.x + f1v*wB.y + f2v*wB.z + f3*wB.w);
  if(lane==0){
    keys[i] = (ull)__double_as_longlong(sc);
    pab[i] = make_float2(pA, pB);
  }
}

// ---- K11: fused radix level: grid hist + last-block pick (ticket) ----------
__global__ void k_histpick(const ull* __restrict__ keys, int N,
                           ull* __restrict__ pref, int* __restrict__ rem,
                           int lev, int* __restrict__ hist, int* __restrict__ ticket){
  __shared__ int h[256];
  __shared__ int lastflag;
  h[threadIdx.x] = 0;
  __syncthreads();
  int shift = 56 - 8*lev;
  ull p = *pref;
  for(int i = blockIdx.x*blockDim.x + threadIdx.x; i<N; i += gridDim.x*blockDim.x){
    ull kk = keys[i];
    if(lev==0 || (kk >> (shift+8)) == (p >> (shift+8)))
      atomicAdd(&h[(int)((kk>>shift)&255)], 1);
  }
  __syncthreads();
  if(h[threadIdx.x])
    __hip_atomic_fetch_add(&hist[threadIdx.x], h[threadIdx.x],
                           __ATOMIC_RELAXED, __HIP_MEMORY_SCOPE_AGENT);
  __threadfence();
  if(threadIdx.x==0){
    int tk = __hip_atomic_fetch_add(ticket, 1, __ATOMIC_ACQ_REL, __HIP_MEMORY_SCOPE_AGENT);
    lastflag = (tk == (int)gridDim.x - 1);
  }
  __syncthreads();
  if(!lastflag) return;
  int v = __hip_atomic_load(&hist[threadIdx.x], __ATOMIC_RELAXED, __HIP_MEMORY_SCOPE_AGENT);
  h[threadIdx.x] = v;
  __syncthreads();
  if(threadIdx.x==0){
    int r = *rem, cum = 0, chosen = 0;
    for(int d=255; d>=0; --d){
      cum += h[d];
      if(cum >= r){ chosen = d; r -= (cum - h[d]); break; }
    }
    *rem = r;
    *pref = p | ((ull)chosen << shift);
  }
}

// ---- K12: q[i] = pB + sel*pA (per-source gate contribution) ----------------
__global__ void k_qval(const float2* __restrict__ pab, const ull* __restrict__ keys,
                       const ull* __restrict__ keyT, float* __restrict__ q, int N){
  int i = blockIdx.x*blockDim.x + threadIdx.x;
  if(i>=N) return;
  float2 p = pab[i];
  q[i] = p.y + ((keys[i] > *keyT) ? p.x : 0.f);
}

// ---- K13: gather C: z = sum q[src]; gg = sel * sigmoid(z+b) ----------------
__global__ void k_gatherC(const int* __restrict__ csr, const int* __restrict__ rowptr,
                          const float* __restrict__ q,
                          const ull* __restrict__ keys, const ull* __restrict__ keyT,
                          const float* __restrict__ lwb,
                          float* __restrict__ gg, int N){
  int lane = threadIdx.x & 63;
  int wid  = (int)((blockIdx.x*(unsigned)blockDim.x + threadIdx.x)>>6);
  int g = lane>>4, t = lane&15;
  int i = wid*4 + g;
  if(i>=N) return;
  int beg = rowptr[i], end = rowptr[i+1];
  float z = 0.f;
  for(int e = beg + t; e < end; e += 16) z += q[csr[e]];
  z = qsumf(z);
  if(t==0){
    float gv = 1.f/(1.f+expf(-(z + lwb[0])));
    gg[i] = (keys[i] > *keyT) ? gv : 0.f;
  }
}

// ---- K14: gather D + final chain (gg-gated row gather) ---------------------
__global__ void k_gatherD(const int* __restrict__ csr, const int* __restrict__ rowptr,
                          const float* __restrict__ xtf, const float* __restrict__ gg,
                          float* __restrict__ out, int N){
  int lane = threadIdx.x & 63;
  int i = (int)((blockIdx.x*(unsigned)blockDim.x + threadIdx.x)>>6);
  if(i>=N) return;
  int beg = rowptr[i], deg = rowptr[i+1]-beg;
  int g = lane>>4, t = lane&15;
  float c0=0.f,c1=0.f,c2=0.f,c3=0.f;
  int j = g;
  int s = (j<deg) ? csr[beg+j] : 0;
  while(j < deg){
    int snext = (j+4<deg) ? csr[beg+j+4] : 0;
    float gv = gg[s];
    if(gv != 0.f){
      float4 v = *((const float4*)(xtf + (size_t)s*64 + t*4));
      c0 = fmaf(gv, v.x, c0); c1 = fmaf(gv, v.y, c1);
      c2 = fmaf(gv, v.z, c2); c3 = fmaf(gv, v.w, c3);
    }
    s = snext; j += 4;
  }
  c0 = gsumf(c0); c1 = gsumf(c1); c2 = gsumf(c2); c3 = gsumf(c3);
  float4 xr = *((const float4*)(xtf + (size_t)i*64 + t*4));
  float v0 = xr.x + fmaxf(c0,0.f);
  float v1 = xr.y + fmaxf(c1,0.f);
  float v2 = xr.z + fmaxf(c2,0.f);
  float v3 = xr.w + fmaxf(c3,0.f);
  float n2 = qsumf(v0*v0 + v1*v1 + v2*v2 + v3*v3);
  float n = fmaxf(sqrtf(n2), 1e-15f);
  float f = tanhf(n)/n;
  float e0=f*v0, e1=f*v1, e2=f*v2, e3=f*v3;
  float en = fmaxf(tanhf(n), 1e-15f);
  if(en > MAXN_F){ float sf = MAXN_F/en; e0*=sf; e1*=sf; e2*=sf; e3*=sf; }
  e0 = fmaxf(e0,0.f); e1 = fmaxf(e1,0.f); e2 = fmaxf(e2,0.f); e3 = fmaxf(e3,0.f);
  float m2 = qsumf(e0*e0 + e1*e1 + e2*e2 + e3*e3);
  float nb = fmaxf(sqrtf(m2), 1e-15f);
  float f2 = tanhf(nb)/nb;
  float o0=f2*e0, o1=f2*e1, o2=f2*e2, o3=f2*e3;
  float on = fmaxf(tanhf(nb), 1e-15f);
  if(on > MAXN_F){ float sf = MAXN_F/on; o0*=sf; o1*=sf; o2*=sf; o3*=sf; }
  if(g==0){
    float4 ov = make_float4(o0,o1,o2,o3);
    *((float4*)(out + (size_t)i*64 + t*4)) = ov;
  }
}

// ---------------------------------------------------------------------------
extern "C" void kernel_launch(void* const* d_in, const int* in_sizes, int n_in,
                              void* d_out, int out_size, void* d_ws, size_t ws_size,
                              hipStream_t stream){
  const float* x    = (const float*)d_in[0];
  const int*   ei   = (const int*)d_in[1];
  const float* W    = (const float*)d_in[2];
  const float* bias = (const float*)d_in[3];
  const float* lww  = (const float*)d_in[4];
  const float* lwb  = (const float*)d_in[5];
  int N = in_sizes[0]/64;
  int E = in_sizes[1]/2;
  int kth = (int)((double)N*0.75);
  int NB = (N+255)>>8;                         // node buckets (256 nodes each)
  if(NB > NBMAX) return;                       // loud failure if N too large
  int chunk = (E + BINBLK - 1)/BINBLK;

  char* ws = (char*)d_ws;
  size_t cur = 0;
  auto alloc = [&](size_t bytes){ size_t o = cur; cur = (cur + bytes + 255) & ~(size_t)255; return o; };
  size_t o_hb   = alloc(64*sizeof(double));
  size_t o_hb2  = alloc(8);
  size_t o_keyT = alloc(8);
  size_t o_rem  = alloc(4);
  size_t o_zero = cur;                         // ---- zeroed region start ----
  size_t o_hist = alloc(8*256*4);              // per-level hist
  size_t o_tick = alloc(8*4);                  // per-level tickets
  size_t o_dTot = alloc((size_t)NBMAX*4);
  size_t o_sTot = alloc((size_t)NBMAX*4);
  size_t zlen   = cur - o_zero;                // ---- zeroed region end ------
  size_t o_dBas = alloc((size_t)(NBMAX+1)*4);
  size_t o_sBas = alloc((size_t)(NBMAX+1)*4);
  size_t o_dCur = alloc((size_t)NBMAX*4);
  size_t o_sCur = alloc((size_t)NBMAX*4);
  size_t o_rowp = alloc((size_t)(N+1)*4);
  size_t o_csr  = alloc((size_t)E*4);
  size_t o_dbin = alloc((size_t)E*8);
  size_t o_sbin = alloc((size_t)E*4);
  size_t o_dinv = alloc((size_t)N*8);
  size_t o_keys = alloc((size_t)N*8);
  size_t o_pab  = alloc((size_t)N*8);
  size_t o_q    = alloc((size_t)N*4);
  size_t o_xtf  = alloc((size_t)N*64*4);
  size_t o_xtd  = alloc((size_t)N*64*8);
  size_t o_mx   = alloc((size_t)N*64*8);
  size_t o_r1   = alloc((size_t)N*8);
  size_t o_r2   = alloc((size_t)N*8);
  size_t o_r3   = alloc((size_t)N*8);
  size_t o_al   = alloc((size_t)N*8);
  size_t o_be   = alloc((size_t)N*8);
  size_t o_gg   = alloc((size_t)N*4);
  if(ws_size < cur) return;                    // loud, clean failure

  double* hb     = (double*)(ws+o_hb);
  double* hb2    = (double*)(ws+o_hb2);
  ull*    keyT   = (ull*)(ws+o_keyT);
  int*    rem    = (int*)(ws+o_rem);
  int*    hist   = (int*)(ws+o_hist);
  int*    tick   = (int*)(ws+o_tick);
  int*    dstTot = (int*)(ws+o_dTot);
  int*    srcTot = (int*)(ws+o_sTot);
  int*    dstBase= (int*)(ws+o_dBas);
  int*    srcBase= (int*)(ws+o_sBas);
  int*    dstCur = (int*)(ws+o_dCur);
  int*    srcCur = (int*)(ws+o_sCur);
  int*    rowptr = (int*)(ws+o_rowp);
  int*    csr    = (int*)(ws+o_csr);
  ull*    dstbin = (ull*)(ws+o_dbin);
  int*    srcbin = (int*)(ws+o_sbin);
  double* dinv   = (double*)(ws+o_dinv);
  ull*    keys   = (ull*)(ws+o_keys);
  float2* pab    = (float2*)(ws+o_pab);
  float*  q      = (float*)(ws+o_q);
  float*  xtf    = (float*)(ws+o_xtf);
  double* xtd    = (double*)(ws+o_xtd);
  double* mx     = (double*)(ws+o_mx);
  double* r1     = (double*)(ws+o_r1);
  double* r2     = (double*)(ws+o_r2);
  double* r3     = (double*)(ws+o_r3);
  double* alpha  = (double*)(ws+o_al);
  double* beta   = (double*)(ws+o_be);
  float*  gg     = (float*)(ws+o_gg);

  hipMemsetAsync(ws+o_zero, 0, zlen, stream);

  int nodeBlocks = (N+3)/4;                    // 1 wave per node
  int rBlocks    = (N+15)/16;                  // 4 nodes per wave
  k_init     <<<1, 64, 0, stream>>>(bias, hb, hb2, keyT, rem, kth);
  k_gemm     <<<(N+NPB-1)/NPB, 256, 0, stream>>>(x, W, mx, N);
  k_reduce   <<<rBlocks, 256, 0, stream>>>(x, mx, hb, r1, r2, r3, N);
  k_chain    <<<(N+255)/256, 256, 0, stream>>>(r1, r2, r3, hb2, alpha, beta, N);
  k_apply    <<<(N*32+255)/256, 256, 0, stream>>>(mx, alpha, beta, hb, xtd, xtf, N);
  k_binCount <<<BINBLK, 256, 0, stream>>>(ei, E, NB, chunk, dstTot, srcTot);
  k_smallScan<<<1, NBMAX, 0, stream>>>(dstTot, srcTot, NB, dstBase, dstCur,
                                       srcBase, srcCur, rowptr, N, E);
  k_binPlace <<<BINBLK, 256, 0, stream>>>(ei, E, NB, chunk, dstCur, srcCur, dstbin, srcbin);
  k_bucketA  <<<NB, 256, 0, stream>>>(dstbin, dstBase, rowptr, csr, N);
  k_bucketB  <<<NB, 256, 0, stream>>>(srcbin, srcBase, dinv, N);
  k_gatherA  <<<nodeBlocks, 256, 0, stream>>>(csr, rowptr, xtf, xtd, dinv, lww, keys, pab, N);
  for(int lev=0; lev<8; ++lev)
    k_histpick<<<256, 256, 0, stream>>>(keys, N, keyT, rem, lev, hist+lev*256, tick+lev);
  k_qval     <<<(N+255)/256, 256, 0, stream>>>(pab, keys, keyT, q, N);
  k_gatherC  <<<rBlocks, 256, 0, stream>>>(csr, rowptr, q, keys, keyT, lwb, gg, N);
  k_gatherD  <<<nodeBlocks, 256, 0, stream>>>(csr, rowptr, xtf, gg, (float*)d_out, N);
}